// Round 7
// baseline (203.626 us; speedup 1.0000x reference)
//
#include <hip/hip_runtime.h>
#include <cstdint>
#include <cstddef>

#define S_   2048
#define D_   2048
#define NH_  32
#define NKV_ 8
#define HD_  64

using bf16x8 = __attribute__((ext_vector_type(8))) __bf16;
using f32x4  = __attribute__((ext_vector_type(4))) float;

#define AS_GLOBAL(p) (const __attribute__((address_space(1))) void*)(p)
#define AS_LDS(p)    (__attribute__((address_space(3))) void*)(p)

// ---------------- f32 -> bf16 bulk convert (vectorized) -------------------
__global__ __launch_bounds__(256) void cvt_f32_bf16(
    const float* __restrict__ in, __bf16* __restrict__ out, int n4) {
  const int i = blockIdx.x * 256 + threadIdx.x;
  if (i >= n4) return;
  const float4 v = reinterpret_cast<const float4*>(in)[i];
  __bf16 t[4] = {(__bf16)v.x, (__bf16)v.y, (__bf16)v.z, (__bf16)v.w};
  reinterpret_cast<uint2*>(out)[i] = *reinterpret_cast<uint2*>(t);
}

// ---------------- bf16 MFMA GEMM core: C[M][N] = A[M][K] * B[N][K]^T ------
__device__ __forceinline__ void gemm_tile_128(
    const __bf16* __restrict__ A, const __bf16* __restrict__ B,
    float* __restrict__ C, int K, int N, int m0, int n0) {
  __shared__ __align__(16) char ldsA[16384];
  __shared__ __align__(16) char ldsB[16384];
  const int tid = threadIdx.x;
  const int l = tid & 63;
  const int w = tid >> 6;
  const int l15 = l & 15, lg = l >> 4;
  const int wm = w >> 1, wn = w & 1;

  f32x4 acc[4][4] = {};

  const int srow   = tid >> 3;
  const int schunk = (tid & 7) ^ (srow & 7);
  const __bf16* gA = A + (size_t)(m0 + srow) * K + schunk * 8;
  const __bf16* gB = B + (size_t)(n0 + srow) * K + schunk * 8;
  const int ldst = tid * 16;

  for (int k0 = 0; k0 < K; k0 += 64) {
    __syncthreads();
#pragma unroll
    for (int i = 0; i < 4; ++i) {
      __builtin_amdgcn_global_load_lds(AS_GLOBAL(gA + (size_t)i*32*K + k0),
                                       AS_LDS(ldsA + i*4096 + ldst), 16, 0, 0);
      __builtin_amdgcn_global_load_lds(AS_GLOBAL(gB + (size_t)i*32*K + k0),
                                       AS_LDS(ldsB + i*4096 + ldst), 16, 0, 0);
    }
    __syncthreads();

    bf16x8 af[4][2], bfr[4][2];
#pragma unroll
    for (int f = 0; f < 4; ++f) {
      const int arow = wm*64 + f*16 + l15;
      const int brow = wn*64 + f*16 + l15;
#pragma unroll
      for (int ks = 0; ks < 2; ++ks) {
        af[f][ks] = *reinterpret_cast<const bf16x8*>(
            ldsA + arow*128 + (((ks*4 + lg) ^ (arow & 7)) << 4));
        bfr[f][ks] = *reinterpret_cast<const bf16x8*>(
            ldsB + brow*128 + (((ks*4 + lg) ^ (brow & 7)) << 4));
      }
    }
#pragma unroll
    for (int mf = 0; mf < 4; ++mf)
#pragma unroll
      for (int nf = 0; nf < 4; ++nf) {
        acc[mf][nf] = __builtin_amdgcn_mfma_f32_16x16x32_bf16(
            af[mf][0], bfr[nf][0], acc[mf][nf], 0, 0, 0);
        acc[mf][nf] = __builtin_amdgcn_mfma_f32_16x16x32_bf16(
            af[mf][1], bfr[nf][1], acc[mf][nf], 0, 0, 0);
      }
  }

#pragma unroll
  for (int mf = 0; mf < 4; ++mf)
#pragma unroll
    for (int nf = 0; nf < 4; ++nf)
#pragma unroll
      for (int r = 0; r < 4; ++r)
        C[(size_t)(m0 + wm*64 + mf*16 + lg*4 + r) * N + n0 + wn*64 + nf*16 + l15]
            = acc[mf][nf][r];
}

// fused Q/K/V projection: grid.x 0..15 -> wq tiles, 16..19 -> wk, 20..23 -> wv
__global__ __launch_bounds__(256) void gemm_qkv(
    const __bf16* __restrict__ hs,
    const __bf16* __restrict__ wq, const __bf16* __restrict__ wk,
    const __bf16* __restrict__ wv,
    float* __restrict__ qp, float* __restrict__ kp, float* __restrict__ vp) {
  const int bx = blockIdx.x;
  const __bf16* Bm; float* Cm; int N, n0;
  if (bx < 16)      { Bm = wq; Cm = qp; N = 2048; n0 = bx * 128; }
  else if (bx < 20) { Bm = wk; Cm = kp; N = 512;  n0 = (bx - 16) * 128; }
  else              { Bm = wv; Cm = vp; N = 512;  n0 = (bx - 20) * 128; }
  gemm_tile_128(hs, Bm, Cm, 2048, N, blockIdx.y * 128, n0);
}

__global__ __launch_bounds__(256) void gemm_wo(
    const __bf16* __restrict__ ypre, const __bf16* __restrict__ wo,
    float* __restrict__ y) {
  gemm_tile_128(ypre, wo, y, 2048, 2048, blockIdx.y * 128, blockIdx.x * 128);
}

// ---------------- RoPE + RMSNorm, q variant -------------------------------
// fold (1/SCALE)*log2(e) into q so flash softmax runs in exp2 domain
__global__ __launch_bounds__(256) void rope_norm_q(
    const float* __restrict__ q, const float* __restrict__ cosT,
    const float* __restrict__ sinT, const float* __restrict__ w,
    __bf16* __restrict__ qbf) {
  const int wid  = (int)((blockIdx.x * 256 + threadIdx.x) >> 6);
  const int lane = threadIdx.x & 63;
  const int s = wid >> 5;
  const int h = wid & 31;
  const size_t idx = (size_t)s*D_ + h*HD_ + lane;
  float val = q[idx];
  const float c  = cosT[s*32 + (lane >> 1)];
  const float sn = sinT[s*32 + (lane >> 1)];
  const float partner = __shfl_xor(val, 1);
  const float ro = (lane & 1) ? fmaf(partner, sn, val*c)
                              : fmaf(val, c, -partner*sn);
  float ssq = ro * ro;
#pragma unroll
  for (int off = 32; off >= 1; off >>= 1) ssq += __shfl_xor(ssq, off);
  const float rinv = rsqrtf(ssq * (1.0f/64.0f) + 1e-5f);
  qbf[idx] = (__bf16)(ro * rinv * w[lane] * 0.180336880111120426f);
}

// ---------------- RoPE + RMSNorm, k variant: kp in place + kbf(bf16) -----
__global__ __launch_bounds__(256) void rope_norm_k(
    float* __restrict__ k, const float* __restrict__ cosT,
    const float* __restrict__ sinT, const float* __restrict__ w,
    __bf16* __restrict__ kbf) {
  const int wid  = (int)((blockIdx.x * 256 + threadIdx.x) >> 6);
  const int lane = threadIdx.x & 63;
  const int s   = wid >> 3;
  const int kvh = wid & 7;
  const size_t idx = (size_t)s*(NKV_*HD_) + kvh*HD_ + lane;
  float val = k[idx];
  const float c  = cosT[s*32 + (lane >> 1)];
  const float sn = sinT[s*32 + (lane >> 1)];
  const float partner = __shfl_xor(val, 1);
  const float ro = (lane & 1) ? fmaf(partner, sn, val*c)
                              : fmaf(val, c, -partner*sn);
  float ssq = ro * ro;
#pragma unroll
  for (int off = 32; off >= 1; off >>= 1) ssq += __shfl_xor(ssq, off);
  const float rinv = rsqrtf(ssq * (1.0f/64.0f) + 1e-5f);
  const float res = ro * rinv * w[lane];
  k[idx] = res;
  kbf[idx] = (__bf16)res;
}

// ---------------- khT output: khT[h][d][s] = k_post[kvh=h/4][s][d] --------
__global__ __launch_bounds__(256) void transpose_khT(
    const float* __restrict__ kpost, float* __restrict__ khT) {
  __shared__ float tl[64][68];
  const int s0  = blockIdx.x * 64;
  const int kvh = blockIdx.y;
  const int t = threadIdx.x;
  {
    const int d0 = (t & 15) * 4;
    const int sl = t >> 4;
#pragma unroll
    for (int rep = 0; rep < 4; ++rep) {
      const int srow = sl + rep*16;
      float4 v = *reinterpret_cast<const float4*>(
          &kpost[(size_t)(s0 + srow)*(NKV_*HD_) + kvh*HD_ + d0]);
      tl[d0+0][srow]=v.x; tl[d0+1][srow]=v.y; tl[d0+2][srow]=v.z; tl[d0+3][srow]=v.w;
    }
  }
  __syncthreads();
  {
    const int d  = t >> 2;
    const int s4 = (t & 3) * 16;
#pragma unroll
    for (int c = 0; c < 4; ++c) {
      float4 v;
      v.x = tl[d][s4+c*4+0]; v.y = tl[d][s4+c*4+1];
      v.z = tl[d][s4+c*4+2]; v.w = tl[d][s4+c*4+3];
#pragma unroll
      for (int r = 0; r < 4; ++r) {
        *reinterpret_cast<float4*>(
            &khT[((size_t)(kvh*4 + r)*HD_ + d)*S_ + s0 + s4 + c*4]) = v;
      }
    }
  }
}

// ---------------- V: vh output (f32, replicated) + vT global (bf16) -------
__global__ __launch_bounds__(256) void transpose_v(
    const float* __restrict__ vp, float* __restrict__ vh,
    __bf16* __restrict__ vtbf) {
  __shared__ float tl[64][68];
  const int s0  = blockIdx.x * 64;
  const int kvh = blockIdx.y;
  const int t = threadIdx.x;
  const int srow = t >> 2, dc = (t & 3) * 16;
  const float* src = &vp[(size_t)(s0 + srow)*(NKV_*HD_) + kvh*HD_ + dc];
  float4 a = reinterpret_cast<const float4*>(src)[0];
  float4 b = reinterpret_cast<const float4*>(src)[1];
  float4 c = reinterpret_cast<const float4*>(src)[2];
  float4 d = reinterpret_cast<const float4*>(src)[3];
  *reinterpret_cast<float4*>(&tl[srow][dc])      = a;
  *reinterpret_cast<float4*>(&tl[srow][dc + 4])  = b;
  *reinterpret_cast<float4*>(&tl[srow][dc + 8])  = c;
  *reinterpret_cast<float4*>(&tl[srow][dc + 12]) = d;
#pragma unroll
  for (int r = 0; r < 4; ++r) {
    float* dst = &vh[((size_t)(kvh*4 + r)*S_ + s0 + srow)*HD_ + dc];
    reinterpret_cast<float4*>(dst)[0] = a;
    reinterpret_cast<float4*>(dst)[1] = b;
    reinterpret_cast<float4*>(dst)[2] = c;
    reinterpret_cast<float4*>(dst)[3] = d;
  }
  __syncthreads();
  const int dr = t >> 2, sc = (t & 3) * 16;
  __bf16 vals[16];
#pragma unroll
  for (int i = 0; i < 16; ++i) vals[i] = (__bf16)tl[sc + i][dr];
  uint4* dst = reinterpret_cast<uint4*>(&vtbf[((size_t)(kvh*64 + dr))*S_ + s0 + sc]);
  dst[0] = reinterpret_cast<uint4*>(vals)[0];
  dst[1] = reinterpret_cast<uint4*>(vals)[1];
}

// ---------------- softmax update (exp2 domain, defer-max T13) -------------
__device__ __forceinline__ void softmax_update(
    f32x4 (&s_)[4], float (&m_)[4], float (&l_)[4], f32x4 (&o_)[4],
    __bf16 (*pldw)[72], int l15, int lg) {
  float mx[4];
#pragma unroll
  for (int r = 0; r < 4; ++r) {
    float t = fmaxf(fmaxf(s_[0][r], s_[1][r]), fmaxf(s_[2][r], s_[3][r]));
#pragma unroll
    for (int off = 8; off >= 1; off >>= 1) t = fmaxf(t, __shfl_xor(t, off));
    mx[r] = t;
  }
  const bool defer = (mx[0] <= m_[0] + 8.f) && (mx[1] <= m_[1] + 8.f) &&
                     (mx[2] <= m_[2] + 8.f) && (mx[3] <= m_[3] + 8.f);
  if (!__all(defer)) {
#pragma unroll
    for (int r = 0; r < 4; ++r) {
      const float mnew = fmaxf(m_[r], mx[r]);
      const float scl = exp2f(m_[r] - mnew);
      m_[r] = mnew;
      l_[r] *= scl;
      o_[0][r] *= scl; o_[1][r] *= scl; o_[2][r] *= scl; o_[3][r] *= scl;
    }
  }
  float rs[4] = {0.f, 0.f, 0.f, 0.f};
#pragma unroll
  for (int nb = 0; nb < 4; ++nb) {
#pragma unroll
    for (int r = 0; r < 4; ++r) {
      const float p = exp2f(s_[nb][r] - m_[r]);
      rs[r] += p;
      pldw[lg*4 + r][nb*16 + l15] = (__bf16)p;
    }
  }
#pragma unroll
  for (int r = 0; r < 4; ++r) {
    float t = rs[r];
#pragma unroll
    for (int off = 8; off >= 1; off >>= 1) t += __shfl_xor(t, off);
    l_[r] += t;
  }
}

// ---------------- causal flash attention, paired q-tiles, A/B interleaved -
__global__ __launch_bounds__(256) void flash_attn_mfma(
    const __bf16* __restrict__ qbf, const __bf16* __restrict__ kbf,
    const __bf16* __restrict__ vtbf, __bf16* __restrict__ ypre) {
  __shared__ __align__(16) char kld[8192];           // K tile, swizzled
  __shared__ __align__(16) char vtl[8192];           // V^T tile, swizzled
  __shared__ __align__(16) __bf16 pldA[4][16][72];   // per-wave P (tile A)
  __shared__ __align__(16) __bf16 pldB[4][16][72];   // per-wave P (tile B)

  const int h   = blockIdx.y;
  const int pi  = blockIdx.x;       // 0..15
  const int qbA = pi, qbB = 31 - pi;
  const int nkt = qbB;
  const int kvh = h >> 2;
  const int tid = threadIdx.x;
  const int l   = tid & 63;
  const int w   = tid >> 6;
  const int l15 = l & 15;
  const int lg  = l >> 4;

  const int j  = tid >> 2;
  const int c0 = (tid & 3) * 16;
  const int b0 = (j*128 + c0*2)      ^ ((j & 7) << 4);
  const int b1 = (j*128 + c0*2 + 16) ^ ((j & 7) << 4);
  const __bf16* ksrc = kbf  + (size_t)j*(NKV_*HD_) + kvh*HD_ + c0;
  const __bf16* vsrc = vtbf + (size_t)(kvh*64 + j)*S_ + c0;

  bf16x8 qfA0, qfA1, qfB0, qfB1;
  {
    const __bf16* qa = qbf + (size_t)(qbA*64 + w*16 + l15)*D_ + h*HD_ + lg*8;
    qfA0 = *reinterpret_cast<const bf16x8*>(qa);
    qfA1 = *reinterpret_cast<const bf16x8*>(qa + 32);
    const __bf16* qb = qbf + (size_t)(qbB*64 + w*16 + l15)*D_ + h*HD_ + lg*8;
    qfB0 = *reinterpret_cast<const bf16x8*>(qb);
    qfB1 = *reinterpret_cast<const bf16x8*>(qb + 32);
  }

  f32x4 oA[4], oB[4];
#pragma unroll
  for (int nb = 0; nb < 4; ++nb) {
    oA[nb] = f32x4{0.f, 0.f, 0.f, 0.f};
    oB[nb] = f32x4{0.f, 0.f, 0.f, 0.f};
  }
  float mA[4] = {-1e30f, -1e30f, -1e30f, -1e30f};
  float lA[4] = {0.f, 0.f, 0.f, 0.f};
  float mB[4] = {-1e30f, -1e30f, -1e30f, -1e30f};
  float lB[4] = {0.f, 0.f, 0.f, 0.f};

  uint4 kr0 = reinterpret_cast<const uint4*>(ksrc)[0];
  uint4 kr1 = reinterpret_cast<const uint4*>(ksrc + 8)[0];
  uint4 vr0 = reinterpret_cast<const uint4*>(vsrc)[0];
  uint4 vr1 = reinterpret_cast<const uint4*>(vsrc + 8)[0];

  for (int kt = 0; kt <= nkt; ++kt) {
    __syncthreads();
    *reinterpret_cast<uint4*>(kld + b0) = kr0;
    *reinterpret_cast<uint4*>(kld + b1) = kr1;
    *reinterpret_cast<uint4*>(vtl + b0) = vr0;
    *reinterpret_cast<uint4*>(vtl + b1) = vr1;
    __syncthreads();

    if (kt < nkt) {   // T14: next tile's loads drain under this tile's compute
      const __bf16* kn = ksrc + (size_t)(kt + 1)*64*(NKV_*HD_);
      const __bf16* vn = vsrc + (size_t)(kt + 1)*64;
      kr0 = reinterpret_cast<const uint4*>(kn)[0];
      kr1 = reinterpret_cast<const uint4*>(kn + 8)[0];
      vr0 = reinterpret_cast<const uint4*>(vn)[0];
      vr1 = reinterpret_cast<const uint4*>(vn + 8)[0];
    }

    const bool aAct = (kt <= qbA);

    // ---- QK^T for both tiles, shared K reads ----
    f32x4 sA[4], sB[4];
#pragma unroll
    for (int nb = 0; nb < 4; ++nb) {
      const int row = nb*16 + l15;
      const int bc  = lg*16;
      const bf16x8 kb0 = *reinterpret_cast<const bf16x8*>(
          kld + ((row*128 + bc)      ^ ((row & 7) << 4)));
      const bf16x8 kb1 = *reinterpret_cast<const bf16x8*>(
          kld + ((row*128 + bc + 64) ^ ((row & 7) << 4)));
      f32x4 t = f32x4{0.f, 0.f, 0.f, 0.f};
      t = __builtin_amdgcn_mfma_f32_16x16x32_bf16(qfB0, kb0, t, 0, 0, 0);
      t = __builtin_amdgcn_mfma_f32_16x16x32_bf16(qfB1, kb1, t, 0, 0, 0);
      sB[nb] = t;
      if (aAct) {
        f32x4 u = f32x4{0.f, 0.f, 0.f, 0.f};
        u = __builtin_amdgcn_mfma_f32_16x16x32_bf16(qfA0, kb0, u, 0, 0, 0);
        u = __builtin_amdgcn_mfma_f32_16x16x32_bf16(qfA1, kb1, u, 0, 0, 0);
        sA[nb] = u;
      }
    }

    // ---- causal masks (diagonal tiles only) ----
    if (kt == qbB) {
#pragma unroll
      for (int nb = 0; nb < 4; ++nb)
#pragma unroll
        for (int r = 0; r < 4; ++r)
          if (nb*16 + l15 > w*16 + lg*4 + r) sB[nb][r] = -1e30f;
    }
    if (aAct && kt == qbA) {
#pragma unroll
      for (int nb = 0; nb < 4; ++nb)
#pragma unroll
        for (int r = 0; r < 4; ++r)
          if (nb*16 + l15 > w*16 + lg*4 + r) sA[nb][r] = -1e30f;
    }

    // ---- softmax (independent chains; compiler interleaves) ----
    softmax_update(sB, mB, lB, oB, pldB[w], l15, lg);
    if (aAct) softmax_update(sA, mA, lA, oA, pldA[w], l15, lg);

    // ---- P fragments ----
    const bf16x8 paB0 = *reinterpret_cast<const bf16x8*>(&pldB[w][l15][lg*8]);
    const bf16x8 paB1 = *reinterpret_cast<const bf16x8*>(&pldB[w][l15][32 + lg*8]);
    bf16x8 paA0, paA1;
    if (aAct) {
      paA0 = *reinterpret_cast<const bf16x8*>(&pldA[w][l15][lg*8]);
      paA1 = *reinterpret_cast<const bf16x8*>(&pldA[w][l15][32 + lg*8]);
    }

    // ---- PV for both tiles, shared V reads ----
#pragma unroll
    for (int nb = 0; nb < 4; ++nb) {
      const int row = nb*16 + l15;
      const int bc  = lg*16;
      const bf16x8 v0 = *reinterpret_cast<const bf16x8*>(
          vtl + ((row*128 + bc)      ^ ((row & 7) << 4)));
      const bf16x8 v1 = *reinterpret_cast<const bf16x8*>(
          vtl + ((row*128 + bc + 64) ^ ((row & 7) << 4)));
      oB[nb] = __builtin_amdgcn_mfma_f32_16x16x32_bf16(paB0, v0, oB[nb], 0, 0, 0);
      oB[nb] = __builtin_amdgcn_mfma_f32_16x16x32_bf16(paB1, v1, oB[nb], 0, 0, 0);
      if (aAct) {
        oA[nb] = __builtin_amdgcn_mfma_f32_16x16x32_bf16(paA0, v0, oA[nb], 0, 0, 0);
        oA[nb] = __builtin_amdgcn_mfma_f32_16x16x32_bf16(paA1, v1, oA[nb], 0, 0, 0);
      }
    }
  }

  // ---- epilogue ----
#pragma unroll
  for (int nb = 0; nb < 4; ++nb) {
#pragma unroll
    for (int r = 0; r < 4; ++r) {
      const int rowA = qbA*64 + w*16 + lg*4 + r;
      const int rowB = qbB*64 + w*16 + lg*4 + r;
      ypre[(size_t)rowA*D_ + h*HD_ + nb*16 + l15] = (__bf16)(oA[nb][r] / lA[r]);
      ypre[(size_t)rowB*D_ + h*HD_ + nb*16 + l15] = (__bf16)(oB[nb][r] / lB[r]);
    }
  }
}

// --------------------------------------------------------------------------
extern "C" void kernel_launch(void* const* d_in, const int* in_sizes, int n_in,
                              void* d_out, int out_size, void* d_ws, size_t ws_size,
                              hipStream_t stream) {
  (void)in_sizes; (void)n_in; (void)out_size;
  const float* hs   = (const float*)d_in[0];
  const float* fcos = (const float*)d_in[1];
  const float* fsin = (const float*)d_in[2];
  const float* wq = (const float*)d_in[4];
  const float* wk = (const float*)d_in[5];
  const float* wv = (const float*)d_in[6];
  const float* wo = (const float*)d_in[7];
  const float* qw = (const float*)d_in[8];
  const float* kw = (const float*)d_in[9];

  float* out = (float*)d_out;
  float* y   = out;                 // 2048*2048
  float* khT = out + 4194304;       // 32*64*2048
  float* vh  = out + 8388608;       // 32*2048*64

  __bf16* qbf   = (__bf16*)y;
  __bf16* kbf   = (__bf16*)((char*)y + 8*1024*1024);
  __bf16* vtbf  = (__bf16*)((char*)y + 10*1024*1024);
  __bf16* hs_bf = (__bf16*)khT;
  __bf16* wq_bf = (__bf16*)((char*)khT + 8*1024*1024);
  __bf16* wk_bf = (__bf16*)vh;
  __bf16* wv_bf = (__bf16*)((char*)vh + 2*1024*1024);

  const size_t need = (size_t)40 * 1024 * 1024;
  if (ws_size < need) return;
  char* ws = (char*)d_ws;
  float*  qp      = (float*)(ws);                    // 16MB
  float*  kp      = (float*)(ws + 16*1024*1024);     //  4MB
  float*  vp      = (float*)(ws + 20*1024*1024);     //  4MB
  __bf16* ypre_bf = (__bf16*)(ws + 24*1024*1024);    //  8MB
  __bf16* wo_bf   = (__bf16*)(ws + 32*1024*1024);    //  8MB

  cvt_f32_bf16<<<4096, 256, 0, stream>>>(hs, hs_bf, 1048576);
  cvt_f32_bf16<<<4096, 256, 0, stream>>>(wq, wq_bf, 1048576);
  cvt_f32_bf16<<<1024, 256, 0, stream>>>(wk, wk_bf, 262144);
  cvt_f32_bf16<<<1024, 256, 0, stream>>>(wv, wv_bf, 262144);
  cvt_f32_bf16<<<4096, 256, 0, stream>>>(wo, wo_bf, 1048576);

  gemm_qkv<<<dim3(24, 16), 256, 0, stream>>>(hs_bf, wq_bf, wk_bf, wv_bf, qp, kp, vp);

  rope_norm_q<<<16384, 256, 0, stream>>>(qp, fcos, fsin, qw, qbf);
  rope_norm_k<<< 4096, 256, 0, stream>>>(kp, fcos, fsin, kw, kbf);

  transpose_khT<<<dim3(32, 8), 256, 0, stream>>>(kp, khT);
  transpose_v<<<dim3(32, 8), 256, 0, stream>>>(vp, vh, vtbf);

  flash_attn_mfma<<<dim3(16, 32), 256, 0, stream>>>(qbf, kbf, vtbf, ypre_bf);

  gemm_wo<<<dim3(16, 16), 256, 0, stream>>>(ypre_bf, wo_bf, y);
}

// Round 8
// 201.934 us; speedup vs baseline: 1.0084x; 1.0084x over previous
//
#include <hip/hip_runtime.h>
#include <cstdint>
#include <cstddef>

#define S_   2048
#define D_   2048
#define NH_  32
#define NKV_ 8
#define HD_  64

using bf16x8 = __attribute__((ext_vector_type(8))) __bf16;
using f32x4  = __attribute__((ext_vector_type(4))) float;

#define AS_GLOBAL(p) (const __attribute__((address_space(1))) void*)(p)
#define AS_LDS(p)    (__attribute__((address_space(3))) void*)(p)

// ---------------- f32 -> bf16 bulk convert (vectorized) -------------------
__global__ __launch_bounds__(256) void cvt_f32_bf16(
    const float* __restrict__ in, __bf16* __restrict__ out, int n4) {
  const int i = blockIdx.x * 256 + threadIdx.x;
  if (i >= n4) return;
  const float4 v = reinterpret_cast<const float4*>(in)[i];
  __bf16 t[4] = {(__bf16)v.x, (__bf16)v.y, (__bf16)v.z, (__bf16)v.w};
  reinterpret_cast<uint2*>(out)[i] = *reinterpret_cast<uint2*>(t);
}

// ---------------- bf16 MFMA GEMM core: C[M][N] = A[M][K] * B[N][K]^T ------
__device__ __forceinline__ void gemm_tile_128(
    const __bf16* __restrict__ A, const __bf16* __restrict__ B,
    float* __restrict__ C, int K, int N, int m0, int n0) {
  __shared__ __align__(16) char ldsA[16384];
  __shared__ __align__(16) char ldsB[16384];
  const int tid = threadIdx.x;
  const int l = tid & 63;
  const int w = tid >> 6;
  const int l15 = l & 15, lg = l >> 4;
  const int wm = w >> 1, wn = w & 1;

  f32x4 acc[4][4] = {};

  const int srow   = tid >> 3;
  const int schunk = (tid & 7) ^ (srow & 7);
  const __bf16* gA = A + (size_t)(m0 + srow) * K + schunk * 8;
  const __bf16* gB = B + (size_t)(n0 + srow) * K + schunk * 8;
  const int ldst = tid * 16;

  for (int k0 = 0; k0 < K; k0 += 64) {
    __syncthreads();
#pragma unroll
    for (int i = 0; i < 4; ++i) {
      __builtin_amdgcn_global_load_lds(AS_GLOBAL(gA + (size_t)i*32*K + k0),
                                       AS_LDS(ldsA + i*4096 + ldst), 16, 0, 0);
      __builtin_amdgcn_global_load_lds(AS_GLOBAL(gB + (size_t)i*32*K + k0),
                                       AS_LDS(ldsB + i*4096 + ldst), 16, 0, 0);
    }
    __syncthreads();

    bf16x8 af[4][2], bfr[4][2];
#pragma unroll
    for (int f = 0; f < 4; ++f) {
      const int arow = wm*64 + f*16 + l15;
      const int brow = wn*64 + f*16 + l15;
#pragma unroll
      for (int ks = 0; ks < 2; ++ks) {
        af[f][ks] = *reinterpret_cast<const bf16x8*>(
            ldsA + arow*128 + (((ks*4 + lg) ^ (arow & 7)) << 4));
        bfr[f][ks] = *reinterpret_cast<const bf16x8*>(
            ldsB + brow*128 + (((ks*4 + lg) ^ (brow & 7)) << 4));
      }
    }
#pragma unroll
    for (int mf = 0; mf < 4; ++mf)
#pragma unroll
      for (int nf = 0; nf < 4; ++nf) {
        acc[mf][nf] = __builtin_amdgcn_mfma_f32_16x16x32_bf16(
            af[mf][0], bfr[nf][0], acc[mf][nf], 0, 0, 0);
        acc[mf][nf] = __builtin_amdgcn_mfma_f32_16x16x32_bf16(
            af[mf][1], bfr[nf][1], acc[mf][nf], 0, 0, 0);
      }
  }

#pragma unroll
  for (int mf = 0; mf < 4; ++mf)
#pragma unroll
    for (int nf = 0; nf < 4; ++nf)
#pragma unroll
      for (int r = 0; r < 4; ++r)
        C[(size_t)(m0 + wm*64 + mf*16 + lg*4 + r) * N + n0 + wn*64 + nf*16 + l15]
            = acc[mf][nf][r];
}

// fused Q/K/V projection: grid.x 0..15 -> wq tiles, 16..19 -> wk, 20..23 -> wv
__global__ __launch_bounds__(256) void gemm_qkv(
    const __bf16* __restrict__ hs,
    const __bf16* __restrict__ wq, const __bf16* __restrict__ wk,
    const __bf16* __restrict__ wv,
    float* __restrict__ qp, float* __restrict__ kp, float* __restrict__ vp) {
  const int bx = blockIdx.x;
  const __bf16* Bm; float* Cm; int N, n0;
  if (bx < 16)      { Bm = wq; Cm = qp; N = 2048; n0 = bx * 128; }
  else if (bx < 20) { Bm = wk; Cm = kp; N = 512;  n0 = (bx - 16) * 128; }
  else              { Bm = wv; Cm = vp; N = 512;  n0 = (bx - 20) * 128; }
  gemm_tile_128(hs, Bm, Cm, 2048, N, blockIdx.y * 128, n0);
}

__global__ __launch_bounds__(256) void gemm_wo(
    const __bf16* __restrict__ ypre, const __bf16* __restrict__ wo,
    float* __restrict__ y) {
  gemm_tile_128(ypre, wo, y, 2048, 2048, blockIdx.y * 128, blockIdx.x * 128);
}

// ---------------- RoPE + RMSNorm, q variant -------------------------------
// fold (1/SCALE)*log2(e) into q so flash softmax runs in exp2 domain
__global__ __launch_bounds__(256) void rope_norm_q(
    const float* __restrict__ q, const float* __restrict__ cosT,
    const float* __restrict__ sinT, const float* __restrict__ w,
    __bf16* __restrict__ qbf) {
  const int wid  = (int)((blockIdx.x * 256 + threadIdx.x) >> 6);
  const int lane = threadIdx.x & 63;
  const int s = wid >> 5;
  const int h = wid & 31;
  const size_t idx = (size_t)s*D_ + h*HD_ + lane;
  float val = q[idx];
  const float c  = cosT[s*32 + (lane >> 1)];
  const float sn = sinT[s*32 + (lane >> 1)];
  const float partner = __shfl_xor(val, 1);
  const float ro = (lane & 1) ? fmaf(partner, sn, val*c)
                              : fmaf(val, c, -partner*sn);
  float ssq = ro * ro;
#pragma unroll
  for (int off = 32; off >= 1; off >>= 1) ssq += __shfl_xor(ssq, off);
  const float rinv = rsqrtf(ssq * (1.0f/64.0f) + 1e-5f);
  qbf[idx] = (__bf16)(ro * rinv * w[lane] * 0.180336880111120426f);
}

// ---------------- RoPE + RMSNorm, k variant: kp in place + kbf(bf16) -----
__global__ __launch_bounds__(256) void rope_norm_k(
    float* __restrict__ k, const float* __restrict__ cosT,
    const float* __restrict__ sinT, const float* __restrict__ w,
    __bf16* __restrict__ kbf) {
  const int wid  = (int)((blockIdx.x * 256 + threadIdx.x) >> 6);
  const int lane = threadIdx.x & 63;
  const int s   = wid >> 3;
  const int kvh = wid & 7;
  const size_t idx = (size_t)s*(NKV_*HD_) + kvh*HD_ + lane;
  float val = k[idx];
  const float c  = cosT[s*32 + (lane >> 1)];
  const float sn = sinT[s*32 + (lane >> 1)];
  const float partner = __shfl_xor(val, 1);
  const float ro = (lane & 1) ? fmaf(partner, sn, val*c)
                              : fmaf(val, c, -partner*sn);
  float ssq = ro * ro;
#pragma unroll
  for (int off = 32; off >= 1; off >>= 1) ssq += __shfl_xor(ssq, off);
  const float rinv = rsqrtf(ssq * (1.0f/64.0f) + 1e-5f);
  const float res = ro * rinv * w[lane];
  k[idx] = res;
  kbf[idx] = (__bf16)res;
}

// ---------------- khT output: khT[h][d][s] = k_post[kvh=h/4][s][d] --------
__global__ __launch_bounds__(256) void transpose_khT(
    const float* __restrict__ kpost, float* __restrict__ khT) {
  __shared__ float tl[64][68];
  const int s0  = blockIdx.x * 64;
  const int kvh = blockIdx.y;
  const int t = threadIdx.x;
  {
    const int d0 = (t & 15) * 4;
    const int sl = t >> 4;
#pragma unroll
    for (int rep = 0; rep < 4; ++rep) {
      const int srow = sl + rep*16;
      float4 v = *reinterpret_cast<const float4*>(
          &kpost[(size_t)(s0 + srow)*(NKV_*HD_) + kvh*HD_ + d0]);
      tl[d0+0][srow]=v.x; tl[d0+1][srow]=v.y; tl[d0+2][srow]=v.z; tl[d0+3][srow]=v.w;
    }
  }
  __syncthreads();
  {
    const int d  = t >> 2;
    const int s4 = (t & 3) * 16;
#pragma unroll
    for (int c = 0; c < 4; ++c) {
      float4 v;
      v.x = tl[d][s4+c*4+0]; v.y = tl[d][s4+c*4+1];
      v.z = tl[d][s4+c*4+2]; v.w = tl[d][s4+c*4+3];
#pragma unroll
      for (int r = 0; r < 4; ++r) {
        *reinterpret_cast<float4*>(
            &khT[((size_t)(kvh*4 + r)*HD_ + d)*S_ + s0 + s4 + c*4]) = v;
      }
    }
  }
}

// ---------------- V: vh output (f32, replicated) + vT global (bf16) -------
__global__ __launch_bounds__(256) void transpose_v(
    const float* __restrict__ vp, float* __restrict__ vh,
    __bf16* __restrict__ vtbf) {
  __shared__ float tl[64][68];
  const int s0  = blockIdx.x * 64;
  const int kvh = blockIdx.y;
  const int t = threadIdx.x;
  const int srow = t >> 2, dc = (t & 3) * 16;
  const float* src = &vp[(size_t)(s0 + srow)*(NKV_*HD_) + kvh*HD_ + dc];
  float4 a = reinterpret_cast<const float4*>(src)[0];
  float4 b = reinterpret_cast<const float4*>(src)[1];
  float4 c = reinterpret_cast<const float4*>(src)[2];
  float4 d = reinterpret_cast<const float4*>(src)[3];
  *reinterpret_cast<float4*>(&tl[srow][dc])      = a;
  *reinterpret_cast<float4*>(&tl[srow][dc + 4])  = b;
  *reinterpret_cast<float4*>(&tl[srow][dc + 8])  = c;
  *reinterpret_cast<float4*>(&tl[srow][dc + 12]) = d;
#pragma unroll
  for (int r = 0; r < 4; ++r) {
    float* dst = &vh[((size_t)(kvh*4 + r)*S_ + s0 + srow)*HD_ + dc];
    reinterpret_cast<float4*>(dst)[0] = a;
    reinterpret_cast<float4*>(dst)[1] = b;
    reinterpret_cast<float4*>(dst)[2] = c;
    reinterpret_cast<float4*>(dst)[3] = d;
  }
  __syncthreads();
  const int dr = t >> 2, sc = (t & 3) * 16;
  __bf16 vals[16];
#pragma unroll
  for (int i = 0; i < 16; ++i) vals[i] = (__bf16)tl[sc + i][dr];
  uint4* dst = reinterpret_cast<uint4*>(&vtbf[((size_t)(kvh*64 + dr))*S_ + s0 + sc]);
  dst[0] = reinterpret_cast<uint4*>(vals)[0];
  dst[1] = reinterpret_cast<uint4*>(vals)[1];
}

// ---------------- flash helpers ------------------------------------------
__device__ __forceinline__ void qk_tile(
    const char* kldh, bf16x8 qf0, bf16x8 qf1, f32x4 (&s_)[4],
    int l15, int lg) {
  __builtin_amdgcn_s_setprio(1);
#pragma unroll
  for (int nb = 0; nb < 4; ++nb) {
    const int row = nb*16 + l15;
    const int bc  = lg*16;
    const bf16x8 kb0 = *reinterpret_cast<const bf16x8*>(
        kldh + row*128 + ((bc)      ^ ((row & 7) << 4)));
    const bf16x8 kb1 = *reinterpret_cast<const bf16x8*>(
        kldh + row*128 + ((bc + 64) ^ ((row & 7) << 4)));
    f32x4 t = f32x4{0.f, 0.f, 0.f, 0.f};
    t = __builtin_amdgcn_mfma_f32_16x16x32_bf16(qf0, kb0, t, 0, 0, 0);
    t = __builtin_amdgcn_mfma_f32_16x16x32_bf16(qf1, kb1, t, 0, 0, 0);
    s_[nb] = t;
  }
  __builtin_amdgcn_s_setprio(0);
}

// softmax in exp2 domain (log2e folded into q prescale) + PV
__device__ __forceinline__ void softmax_pv(
    f32x4 (&s_)[4], float (&m_)[4], float (&l_)[4], f32x4 (&o_)[4],
    __bf16 (*pldw)[72], const char* vbase, int l15, int lg) {
  float scl[4];
#pragma unroll
  for (int r = 0; r < 4; ++r) {
    float mx = fmaxf(fmaxf(s_[0][r], s_[1][r]), fmaxf(s_[2][r], s_[3][r]));
#pragma unroll
    for (int off = 8; off >= 1; off >>= 1) mx = fmaxf(mx, __shfl_xor(mx, off));
    const float mnew = fmaxf(m_[r], mx);
    scl[r] = exp2f(m_[r] - mnew);
    m_[r] = mnew;
  }
  float rs[4] = {0.f, 0.f, 0.f, 0.f};
#pragma unroll
  for (int nb = 0; nb < 4; ++nb) {
#pragma unroll
    for (int r = 0; r < 4; ++r) {
      const float p = exp2f(s_[nb][r] - m_[r]);
      rs[r] += p;
      pldw[lg*4 + r][nb*16 + l15] = (__bf16)p;
    }
  }
#pragma unroll
  for (int r = 0; r < 4; ++r) {
    float t = rs[r];
#pragma unroll
    for (int off = 8; off >= 1; off >>= 1) t += __shfl_xor(t, off);
    l_[r] = l_[r]*scl[r] + t;
    o_[0][r] *= scl[r]; o_[1][r] *= scl[r]; o_[2][r] *= scl[r]; o_[3][r] *= scl[r];
  }
  const bf16x8 pa0 = *reinterpret_cast<const bf16x8*>(&pldw[l15][lg*8]);
  const bf16x8 pa1 = *reinterpret_cast<const bf16x8*>(&pldw[l15][32 + lg*8]);
  __builtin_amdgcn_s_setprio(1);
#pragma unroll
  for (int nb = 0; nb < 4; ++nb) {
    const int row = nb*16 + l15;
    const int bc  = lg*16;
    const bf16x8 v0 = *reinterpret_cast<const bf16x8*>(
        vbase + row*256 + ((bc)      ^ ((row & 7) << 4)));
    const bf16x8 v1 = *reinterpret_cast<const bf16x8*>(
        vbase + row*256 + ((bc + 64) ^ ((row & 7) << 4)));
    f32x4 t = o_[nb];
    t = __builtin_amdgcn_mfma_f32_16x16x32_bf16(pa0, v0, t, 0, 0, 0);
    t = __builtin_amdgcn_mfma_f32_16x16x32_bf16(pa1, v1, t, 0, 0, 0);
    o_[nb] = t;
  }
  __builtin_amdgcn_s_setprio(0);
}

__device__ __forceinline__ void mask_diag(f32x4 (&s_)[4], int l15, int lg, int w) {
#pragma unroll
  for (int nb = 0; nb < 4; ++nb)
#pragma unroll
    for (int r = 0; r < 4; ++r)
      if (nb*16 + l15 > w*16 + lg*4 + r) s_[nb][r] = -1e30f;
}

// ---------------- causal flash attention, paired q-tiles, KVBLK=128 -------
// block = (pair i, head): q-tile A = i, q-tile B = 31-i (64 rows each).
// Staged tile = 128 keys (two 64-key halves), shared between A and B.
__global__ __launch_bounds__(256) void flash_attn_mfma(
    const __bf16* __restrict__ qbf, const __bf16* __restrict__ kbf,
    const __bf16* __restrict__ vtbf, __bf16* __restrict__ ypre) {
  __shared__ __align__(16) char kld[16384];         // K: [128 j][128B], swizzled
  __shared__ __align__(16) char vtl[16384];         // V^T: [64 d][256B], swizzled
  __shared__ __align__(16) __bf16 pld[4][16][72];   // per-wave P (reused A/B)

  const int h   = blockIdx.y;
  const int pi  = blockIdx.x;       // 0..15
  const int qbA = pi, qbB = 31 - pi;
  const int nst = (qbB >> 1) + 1;   // staged 128-key tiles
  const int kvh = h >> 2;
  const int tid = threadIdx.x;
  const int l   = tid & 63;
  const int w   = tid >> 6;
  const int l15 = l & 15;
  const int lg  = l >> 4;

  // K staging: thread t -> key j = t>>1 (0..127), 64B chunk (t&1)
  const int jk = tid >> 1;
  const int ck = (tid & 1) * 32;    // d offset (elements)
  const __bf16* ksrc = kbf + (size_t)jk*(NKV_*HD_) + kvh*HD_ + ck;
  // V staging: thread t -> d = t>>2 (0..63), key chunk (t&3)*32
  const int dv = tid >> 2;
  const int cv = (tid & 3) * 32;    // key offset (elements)
  const __bf16* vsrc = vtbf + (size_t)(kvh*64 + dv)*S_ + cv;

  bf16x8 qfA0, qfA1, qfB0, qfB1;
  {
    const __bf16* qa = qbf + (size_t)(qbA*64 + w*16 + l15)*D_ + h*HD_ + lg*8;
    qfA0 = *reinterpret_cast<const bf16x8*>(qa);
    qfA1 = *reinterpret_cast<const bf16x8*>(qa + 32);
    const __bf16* qb = qbf + (size_t)(qbB*64 + w*16 + l15)*D_ + h*HD_ + lg*8;
    qfB0 = *reinterpret_cast<const bf16x8*>(qb);
    qfB1 = *reinterpret_cast<const bf16x8*>(qb + 32);
  }

  f32x4 oA[4], oB[4];
#pragma unroll
  for (int nb = 0; nb < 4; ++nb) {
    oA[nb] = f32x4{0.f, 0.f, 0.f, 0.f};
    oB[nb] = f32x4{0.f, 0.f, 0.f, 0.f};
  }
  float mA[4] = {-1e30f, -1e30f, -1e30f, -1e30f};
  float lA[4] = {0.f, 0.f, 0.f, 0.f};
  float mB[4] = {-1e30f, -1e30f, -1e30f, -1e30f};
  float lB[4] = {0.f, 0.f, 0.f, 0.f};

  // prologue: prefetch staged tile 0 (4x16B K + 4x16B V per thread)
  uint4 kq0 = reinterpret_cast<const uint4*>(ksrc)[0];
  uint4 kq1 = reinterpret_cast<const uint4*>(ksrc + 8)[0];
  uint4 kq2 = reinterpret_cast<const uint4*>(ksrc + 16)[0];
  uint4 kq3 = reinterpret_cast<const uint4*>(ksrc + 24)[0];
  uint4 vq0 = reinterpret_cast<const uint4*>(vsrc)[0];
  uint4 vq1 = reinterpret_cast<const uint4*>(vsrc + 8)[0];
  uint4 vq2 = reinterpret_cast<const uint4*>(vsrc + 16)[0];
  uint4 vq3 = reinterpret_cast<const uint4*>(vsrc + 24)[0];

  // LDS store addresses (swizzled)
  const int kbb = jk*128 + ck*2;
  const int ksw = (jk & 7) << 4;
  const int vbb = dv*256 + cv*2;
  const int vsw = (dv & 7) << 4;

  for (int st = 0; st < nst; ++st) {
    __syncthreads();
    *reinterpret_cast<uint4*>(kld + ((kbb)      ^ ksw)) = kq0;
    *reinterpret_cast<uint4*>(kld + ((kbb + 16) ^ ksw)) = kq1;
    *reinterpret_cast<uint4*>(kld + ((kbb + 32) ^ ksw)) = kq2;
    *reinterpret_cast<uint4*>(kld + ((kbb + 48) ^ ksw)) = kq3;
    *reinterpret_cast<uint4*>(vtl + ((vbb)      ^ vsw)) = vq0;
    *reinterpret_cast<uint4*>(vtl + ((vbb + 16) ^ vsw)) = vq1;
    *reinterpret_cast<uint4*>(vtl + ((vbb + 32) ^ vsw)) = vq2;
    *reinterpret_cast<uint4*>(vtl + ((vbb + 48) ^ vsw)) = vq3;
    __syncthreads();

    if (st + 1 < nst) {   // T14: next tile's loads drain under compute
      const __bf16* kn = ksrc + (size_t)(st + 1)*128*(NKV_*HD_);
      const __bf16* vn = vsrc + (size_t)(st + 1)*128;
      kq0 = reinterpret_cast<const uint4*>(kn)[0];
      kq1 = reinterpret_cast<const uint4*>(kn + 8)[0];
      kq2 = reinterpret_cast<const uint4*>(kn + 16)[0];
      kq3 = reinterpret_cast<const uint4*>(kn + 24)[0];
      vq0 = reinterpret_cast<const uint4*>(vn)[0];
      vq1 = reinterpret_cast<const uint4*>(vn + 8)[0];
      vq2 = reinterpret_cast<const uint4*>(vn + 16)[0];
      vq3 = reinterpret_cast<const uint4*>(vn + 24)[0];
    }

#pragma unroll
    for (int hf = 0; hf < 2; ++hf) {
      const int hg = 2*st + hf;               // global 64-key block index
      const char* kldh  = kld + hf*8192;
      const char* vbase = vtl + hf*128;
      if (hg <= qbB) {
        f32x4 s_[4];
        qk_tile(kldh, qfB0, qfB1, s_, l15, lg);
        if (hg == qbB) mask_diag(s_, l15, lg, w);
        softmax_pv(s_, mB, lB, oB, pld[w], vbase, l15, lg);
      }
      if (hg <= qbA) {
        f32x4 s_[4];
        qk_tile(kldh, qfA0, qfA1, s_, l15, lg);
        if (hg == qbA) mask_diag(s_, l15, lg, w);
        softmax_pv(s_, mA, lA, oA, pld[w], vbase, l15, lg);
      }
    }
  }

  // ---- epilogue (bf16 — only consumed by the wo GEMM) ----
#pragma unroll
  for (int nb = 0; nb < 4; ++nb) {
#pragma unroll
    for (int r = 0; r < 4; ++r) {
      const int rowA = qbA*64 + w*16 + lg*4 + r;
      const int rowB = qbB*64 + w*16 + lg*4 + r;
      ypre[(size_t)rowA*D_ + h*HD_ + nb*16 + l15] = (__bf16)(oA[nb][r] / lA[r]);
      ypre[(size_t)rowB*D_ + h*HD_ + nb*16 + l15] = (__bf16)(oB[nb][r] / lB[r]);
    }
  }
}

// --------------------------------------------------------------------------
extern "C" void kernel_launch(void* const* d_in, const int* in_sizes, int n_in,
                              void* d_out, int out_size, void* d_ws, size_t ws_size,
                              hipStream_t stream) {
  (void)in_sizes; (void)n_in; (void)out_size;
  const float* hs   = (const float*)d_in[0];
  const float* fcos = (const float*)d_in[1];
  const float* fsin = (const float*)d_in[2];
  const float* wq = (const float*)d_in[4];
  const float* wk = (const float*)d_in[5];
  const float* wv = (const float*)d_in[6];
  const float* wo = (const float*)d_in[7];
  const float* qw = (const float*)d_in[8];
  const float* kw = (const float*)d_in[9];

  float* out = (float*)d_out;
  float* y   = out;                 // 2048*2048
  float* khT = out + 4194304;       // 32*64*2048
  float* vh  = out + 8388608;       // 32*2048*64

  __bf16* qbf   = (__bf16*)y;
  __bf16* kbf   = (__bf16*)((char*)y + 8*1024*1024);
  __bf16* vtbf  = (__bf16*)((char*)y + 10*1024*1024);
  __bf16* hs_bf = (__bf16*)khT;
  __bf16* wq_bf = (__bf16*)((char*)khT + 8*1024*1024);
  __bf16* wk_bf = (__bf16*)vh;
  __bf16* wv_bf = (__bf16*)((char*)vh + 2*1024*1024);

  const size_t need = (size_t)40 * 1024 * 1024;
  if (ws_size < need) return;
  char* ws = (char*)d_ws;
  float*  qp      = (float*)(ws);                    // 16MB
  float*  kp      = (float*)(ws + 16*1024*1024);     //  4MB
  float*  vp      = (float*)(ws + 20*1024*1024);     //  4MB
  __bf16* ypre_bf = (__bf16*)(ws + 24*1024*1024);    //  8MB
  __bf16* wo_bf   = (__bf16*)(ws + 32*1024*1024);    //  8MB

  cvt_f32_bf16<<<4096, 256, 0, stream>>>(hs, hs_bf, 1048576);
  cvt_f32_bf16<<<4096, 256, 0, stream>>>(wq, wq_bf, 1048576);
  cvt_f32_bf16<<<1024, 256, 0, stream>>>(wk, wk_bf, 262144);
  cvt_f32_bf16<<<1024, 256, 0, stream>>>(wv, wv_bf, 262144);
  cvt_f32_bf16<<<4096, 256, 0, stream>>>(wo, wo_bf, 1048576);

  gemm_qkv<<<dim3(24, 16), 256, 0, stream>>>(hs_bf, wq_bf, wk_bf, wv_bf, qp, kp, vp);

  rope_norm_q<<<16384, 256, 0, stream>>>(qp, fcos, fsin, qw, qbf);
  rope_norm_k<<< 4096, 256, 0, stream>>>(kp, fcos, fsin, kw, kbf);

  transpose_khT<<<dim3(32, 8), 256, 0, stream>>>(kp, khT);
  transpose_v<<<dim3(32, 8), 256, 0, stream>>>(vp, vh, vtbf);

  flash_attn_mfma<<<dim3(16, 32), 256, 0, stream>>>(qbf, kbf, vtbf, ypre_bf);

  gemm_wo<<<dim3(16, 16), 256, 0, stream>>>(ypre_bf, wo_bf, y);
}

// Round 9
// 187.795 us; speedup vs baseline: 1.0843x; 1.0753x over previous
//
#include <hip/hip_runtime.h>
#include <cstdint>
#include <cstddef>

#define S_   2048
#define D_   2048
#define NH_  32
#define NKV_ 8
#define HD_  64

using bf16x8 = __attribute__((ext_vector_type(8))) __bf16;
using f32x4  = __attribute__((ext_vector_type(4))) float;

#define AS_GLOBAL(p) (const __attribute__((address_space(1))) void*)(p)
#define AS_LDS(p)    (__attribute__((address_space(3))) void*)(p)

// ---------------- fused f32 -> bf16 bulk convert (5 regions) --------------
__global__ __launch_bounds__(256) void cvt_all(
    const float* __restrict__ hs, const float* __restrict__ wq,
    const float* __restrict__ wk, const float* __restrict__ wv,
    const float* __restrict__ wo,
    __bf16* __restrict__ hs_bf, __bf16* __restrict__ wq_bf,
    __bf16* __restrict__ wk_bf, __bf16* __restrict__ wv_bf,
    __bf16* __restrict__ wo_bf) {
  int i = blockIdx.x * 256 + threadIdx.x;   // float4 index; total 3670016
  const float* src; __bf16* dst; int base;
  if (i < 1048576)      { src = hs; dst = hs_bf; base = 0; }
  else if (i < 2097152) { src = wq; dst = wq_bf; base = 1048576; }
  else if (i < 2359296) { src = wk; dst = wk_bf; base = 2097152; }
  else if (i < 2621440) { src = wv; dst = wv_bf; base = 2359296; }
  else                  { src = wo; dst = wo_bf; base = 2621440; }
  i -= base;
  const float4 v = reinterpret_cast<const float4*>(src)[i];
  __bf16 t[4] = {(__bf16)v.x, (__bf16)v.y, (__bf16)v.z, (__bf16)v.w};
  reinterpret_cast<uint2*>(dst)[i] = *reinterpret_cast<uint2*>(t);
}

// ---------------- bf16 MFMA GEMM core: C[M][N] = A[M][K] * B[N][K]^T ------
__device__ __forceinline__ void gemm_tile_128(
    const __bf16* __restrict__ A, const __bf16* __restrict__ B,
    float* __restrict__ C, int K, int N, int m0, int n0) {
  __shared__ __align__(16) char ldsA[16384];
  __shared__ __align__(16) char ldsB[16384];
  const int tid = threadIdx.x;
  const int l = tid & 63;
  const int w = tid >> 6;
  const int l15 = l & 15, lg = l >> 4;
  const int wm = w >> 1, wn = w & 1;

  f32x4 acc[4][4] = {};

  const int srow   = tid >> 3;
  const int schunk = (tid & 7) ^ (srow & 7);
  const __bf16* gA = A + (size_t)(m0 + srow) * K + schunk * 8;
  const __bf16* gB = B + (size_t)(n0 + srow) * K + schunk * 8;
  const int ldst = tid * 16;

  for (int k0 = 0; k0 < K; k0 += 64) {
    __syncthreads();
#pragma unroll
    for (int i = 0; i < 4; ++i) {
      __builtin_amdgcn_global_load_lds(AS_GLOBAL(gA + (size_t)i*32*K + k0),
                                       AS_LDS(ldsA + i*4096 + ldst), 16, 0, 0);
      __builtin_amdgcn_global_load_lds(AS_GLOBAL(gB + (size_t)i*32*K + k0),
                                       AS_LDS(ldsB + i*4096 + ldst), 16, 0, 0);
    }
    __syncthreads();

    bf16x8 af[4][2], bfr[4][2];
#pragma unroll
    for (int f = 0; f < 4; ++f) {
      const int arow = wm*64 + f*16 + l15;
      const int brow = wn*64 + f*16 + l15;
#pragma unroll
      for (int ks = 0; ks < 2; ++ks) {
        af[f][ks] = *reinterpret_cast<const bf16x8*>(
            ldsA + arow*128 + (((ks*4 + lg) ^ (arow & 7)) << 4));
        bfr[f][ks] = *reinterpret_cast<const bf16x8*>(
            ldsB + brow*128 + (((ks*4 + lg) ^ (brow & 7)) << 4));
      }
    }
#pragma unroll
    for (int mf = 0; mf < 4; ++mf)
#pragma unroll
      for (int nf = 0; nf < 4; ++nf) {
        acc[mf][nf] = __builtin_amdgcn_mfma_f32_16x16x32_bf16(
            af[mf][0], bfr[nf][0], acc[mf][nf], 0, 0, 0);
        acc[mf][nf] = __builtin_amdgcn_mfma_f32_16x16x32_bf16(
            af[mf][1], bfr[nf][1], acc[mf][nf], 0, 0, 0);
      }
  }

#pragma unroll
  for (int mf = 0; mf < 4; ++mf)
#pragma unroll
    for (int nf = 0; nf < 4; ++nf)
#pragma unroll
      for (int r = 0; r < 4; ++r)
        C[(size_t)(m0 + wm*64 + mf*16 + lg*4 + r) * N + n0 + wn*64 + nf*16 + l15]
            = acc[mf][nf][r];
}

// fused Q/K/V projection: grid.x 0..15 -> wq tiles, 16..19 -> wk, 20..23 -> wv
__global__ __launch_bounds__(256) void gemm_qkv(
    const __bf16* __restrict__ hs,
    const __bf16* __restrict__ wq, const __bf16* __restrict__ wk,
    const __bf16* __restrict__ wv,
    float* __restrict__ qp, float* __restrict__ kp, float* __restrict__ vp) {
  const int bx = blockIdx.x;
  const __bf16* Bm; float* Cm; int N, n0;
  if (bx < 16)      { Bm = wq; Cm = qp; N = 2048; n0 = bx * 128; }
  else if (bx < 20) { Bm = wk; Cm = kp; N = 512;  n0 = (bx - 16) * 128; }
  else              { Bm = wv; Cm = vp; N = 512;  n0 = (bx - 20) * 128; }
  gemm_tile_128(hs, Bm, Cm, 2048, N, blockIdx.y * 128, n0);
}

__global__ __launch_bounds__(256) void gemm_wo(
    const __bf16* __restrict__ ypre, const __bf16* __restrict__ wo,
    float* __restrict__ y) {
  gemm_tile_128(ypre, wo, y, 2048, 2048, blockIdx.y * 128, blockIdx.x * 128);
}

// ---------------- RoPE + RMSNorm, q variant -------------------------------
// fold (1/SCALE)*log2(e) into q so flash softmax runs in exp2 domain
__global__ __launch_bounds__(256) void rope_norm_q(
    const float* __restrict__ q, const float* __restrict__ cosT,
    const float* __restrict__ sinT, const float* __restrict__ w,
    __bf16* __restrict__ qbf) {
  const int wid  = (int)((blockIdx.x * 256 + threadIdx.x) >> 6);
  const int lane = threadIdx.x & 63;
  const int s = wid >> 5;
  const int h = wid & 31;
  const size_t idx = (size_t)s*D_ + h*HD_ + lane;
  float val = q[idx];
  const float c  = cosT[s*32 + (lane >> 1)];
  const float sn = sinT[s*32 + (lane >> 1)];
  const float partner = __shfl_xor(val, 1);
  const float ro = (lane & 1) ? fmaf(partner, sn, val*c)
                              : fmaf(val, c, -partner*sn);
  float ssq = ro * ro;
#pragma unroll
  for (int off = 32; off >= 1; off >>= 1) ssq += __shfl_xor(ssq, off);
  const float rinv = rsqrtf(ssq * (1.0f/64.0f) + 1e-5f);
  qbf[idx] = (__bf16)(ro * rinv * w[lane] * 0.180336880111120426f);
}

// ---------------- RoPE + RMSNorm, k variant: kp in place + kbf(bf16) -----
__global__ __launch_bounds__(256) void rope_norm_k(
    float* __restrict__ k, const float* __restrict__ cosT,
    const float* __restrict__ sinT, const float* __restrict__ w,
    __bf16* __restrict__ kbf) {
  const int wid  = (int)((blockIdx.x * 256 + threadIdx.x) >> 6);
  const int lane = threadIdx.x & 63;
  const int s   = wid >> 3;
  const int kvh = wid & 7;
  const size_t idx = (size_t)s*(NKV_*HD_) + kvh*HD_ + lane;
  float val = k[idx];
  const float c  = cosT[s*32 + (lane >> 1)];
  const float sn = sinT[s*32 + (lane >> 1)];
  const float partner = __shfl_xor(val, 1);
  const float ro = (lane & 1) ? fmaf(partner, sn, val*c)
                              : fmaf(val, c, -partner*sn);
  float ssq = ro * ro;
#pragma unroll
  for (int off = 32; off >= 1; off >>= 1) ssq += __shfl_xor(ssq, off);
  const float rinv = rsqrtf(ssq * (1.0f/64.0f) + 1e-5f);
  const float res = ro * rinv * w[lane];
  k[idx] = res;
  kbf[idx] = (__bf16)res;
}

// ---------------- khT output: khT[h][d][s] = k_post[kvh=h/4][s][d] --------
__global__ __launch_bounds__(256) void transpose_khT(
    const float* __restrict__ kpost, float* __restrict__ khT) {
  __shared__ float tl[64][68];
  const int s0  = blockIdx.x * 64;
  const int kvh = blockIdx.y;
  const int t = threadIdx.x;
  {
    const int d0 = (t & 15) * 4;
    const int sl = t >> 4;
#pragma unroll
    for (int rep = 0; rep < 4; ++rep) {
      const int srow = sl + rep*16;
      float4 v = *reinterpret_cast<const float4*>(
          &kpost[(size_t)(s0 + srow)*(NKV_*HD_) + kvh*HD_ + d0]);
      tl[d0+0][srow]=v.x; tl[d0+1][srow]=v.y; tl[d0+2][srow]=v.z; tl[d0+3][srow]=v.w;
    }
  }
  __syncthreads();
  {
    const int d  = t >> 2;
    const int s4 = (t & 3) * 16;
#pragma unroll
    for (int c = 0; c < 4; ++c) {
      float4 v;
      v.x = tl[d][s4+c*4+0]; v.y = tl[d][s4+c*4+1];
      v.z = tl[d][s4+c*4+2]; v.w = tl[d][s4+c*4+3];
#pragma unroll
      for (int r = 0; r < 4; ++r) {
        *reinterpret_cast<float4*>(
            &khT[((size_t)(kvh*4 + r)*HD_ + d)*S_ + s0 + s4 + c*4]) = v;
      }
    }
  }
}

// ---------------- V: vh output (f32, replicated) + vT global (bf16) -------
__global__ __launch_bounds__(256) void transpose_v(
    const float* __restrict__ vp, float* __restrict__ vh,
    __bf16* __restrict__ vtbf) {
  __shared__ float tl[64][68];
  const int s0  = blockIdx.x * 64;
  const int kvh = blockIdx.y;
  const int t = threadIdx.x;
  const int srow = t >> 2, dc = (t & 3) * 16;
  const float* src = &vp[(size_t)(s0 + srow)*(NKV_*HD_) + kvh*HD_ + dc];
  float4 a = reinterpret_cast<const float4*>(src)[0];
  float4 b = reinterpret_cast<const float4*>(src)[1];
  float4 c = reinterpret_cast<const float4*>(src)[2];
  float4 d = reinterpret_cast<const float4*>(src)[3];
  *reinterpret_cast<float4*>(&tl[srow][dc])      = a;
  *reinterpret_cast<float4*>(&tl[srow][dc + 4])  = b;
  *reinterpret_cast<float4*>(&tl[srow][dc + 8])  = c;
  *reinterpret_cast<float4*>(&tl[srow][dc + 12]) = d;
#pragma unroll
  for (int r = 0; r < 4; ++r) {
    float* dst = &vh[((size_t)(kvh*4 + r)*S_ + s0 + srow)*HD_ + dc];
    reinterpret_cast<float4*>(dst)[0] = a;
    reinterpret_cast<float4*>(dst)[1] = b;
    reinterpret_cast<float4*>(dst)[2] = c;
    reinterpret_cast<float4*>(dst)[3] = d;
  }
  __syncthreads();
  const int dr = t >> 2, sc = (t & 3) * 16;
  __bf16 vals[16];
#pragma unroll
  for (int i = 0; i < 16; ++i) vals[i] = (__bf16)tl[sc + i][dr];
  uint4* dst = reinterpret_cast<uint4*>(&vtbf[((size_t)(kvh*64 + dr))*S_ + s0 + sc]);
  dst[0] = reinterpret_cast<uint4*>(vals)[0];
  dst[1] = reinterpret_cast<uint4*>(vals)[1];
}

// ---------------- flash helpers ------------------------------------------
__device__ __forceinline__ void qk_tile(
    const char* kldh, bf16x8 qf0, bf16x8 qf1, f32x4 (&s_)[4],
    int l15, int lg) {
  __builtin_amdgcn_s_setprio(1);
#pragma unroll
  for (int nb = 0; nb < 4; ++nb) {
    const int row = nb*16 + l15;
    const int bc  = lg*16;
    const bf16x8 kb0 = *reinterpret_cast<const bf16x8*>(
        kldh + row*128 + ((bc)      ^ ((row & 7) << 4)));
    const bf16x8 kb1 = *reinterpret_cast<const bf16x8*>(
        kldh + row*128 + ((bc + 64) ^ ((row & 7) << 4)));
    f32x4 t = f32x4{0.f, 0.f, 0.f, 0.f};
    t = __builtin_amdgcn_mfma_f32_16x16x32_bf16(qf0, kb0, t, 0, 0, 0);
    t = __builtin_amdgcn_mfma_f32_16x16x32_bf16(qf1, kb1, t, 0, 0, 0);
    s_[nb] = t;
  }
  __builtin_amdgcn_s_setprio(0);
}

// softmax in exp2 domain (log2e folded into q prescale) + PV
__device__ __forceinline__ void softmax_pv(
    f32x4 (&s_)[4], float (&m_)[4], float (&l_)[4], f32x4 (&o_)[4],
    __bf16 (*pldw)[72], const char* vbase, int l15, int lg) {
  float scl[4];
#pragma unroll
  for (int r = 0; r < 4; ++r) {
    float mx = fmaxf(fmaxf(s_[0][r], s_[1][r]), fmaxf(s_[2][r], s_[3][r]));
#pragma unroll
    for (int off = 8; off >= 1; off >>= 1) mx = fmaxf(mx, __shfl_xor(mx, off));
    const float mnew = fmaxf(m_[r], mx);
    scl[r] = exp2f(m_[r] - mnew);
    m_[r] = mnew;
  }
  float rs[4] = {0.f, 0.f, 0.f, 0.f};
#pragma unroll
  for (int nb = 0; nb < 4; ++nb) {
#pragma unroll
    for (int r = 0; r < 4; ++r) {
      const float p = exp2f(s_[nb][r] - m_[r]);
      rs[r] += p;
      pldw[lg*4 + r][nb*16 + l15] = (__bf16)p;
    }
  }
#pragma unroll
  for (int r = 0; r < 4; ++r) {
    float t = rs[r];
#pragma unroll
    for (int off = 8; off >= 1; off >>= 1) t += __shfl_xor(t, off);
    l_[r] = l_[r]*scl[r] + t;
    o_[0][r] *= scl[r]; o_[1][r] *= scl[r]; o_[2][r] *= scl[r]; o_[3][r] *= scl[r];
  }
  const bf16x8 pa0 = *reinterpret_cast<const bf16x8*>(&pldw[l15][lg*8]);
  const bf16x8 pa1 = *reinterpret_cast<const bf16x8*>(&pldw[l15][32 + lg*8]);
  __builtin_amdgcn_s_setprio(1);
#pragma unroll
  for (int nb = 0; nb < 4; ++nb) {
    const int row = nb*16 + l15;
    const int bc  = lg*16;
    const bf16x8 v0 = *reinterpret_cast<const bf16x8*>(
        vbase + row*128 + ((bc)      ^ ((row & 7) << 4)));
    const bf16x8 v1 = *reinterpret_cast<const bf16x8*>(
        vbase + row*128 + ((bc + 64) ^ ((row & 7) << 4)));
    f32x4 t = o_[nb];
    t = __builtin_amdgcn_mfma_f32_16x16x32_bf16(pa0, v0, t, 0, 0, 0);
    t = __builtin_amdgcn_mfma_f32_16x16x32_bf16(pa1, v1, t, 0, 0, 0);
    o_[nb] = t;
  }
  __builtin_amdgcn_s_setprio(0);
}

__device__ __forceinline__ void mask_diag(f32x4 (&s_)[4], int l15, int lg, int wg) {
#pragma unroll
  for (int nb = 0; nb < 4; ++nb)
#pragma unroll
    for (int r = 0; r < 4; ++r)
      if (nb*16 + l15 > wg*16 + lg*4 + r) s_[nb][r] = -1e30f;
}

// ---------------- causal flash attention, paired q-tiles, kt-parity split -
// block = (pair i, head), 512 threads = 8 waves. Wave-group g (waves 4g..4g+3)
// processes kt = 2*st + g for BOTH q-tiles A=i, B=31-i (rows wg*16 per wave).
// Each group stages its own 64-key K/V buffer (R6 pattern). Partial (m,l,o)
// per parity merged at the end through LDS.
__global__ __launch_bounds__(512, 4) void flash_attn_mfma(
    const __bf16* __restrict__ qbf, const __bf16* __restrict__ kbf,
    const __bf16* __restrict__ vtbf, __bf16* __restrict__ ypre) {
  __shared__ __align__(16) char smem[51200];
  // loop phase: kld[g] = smem + g*8192; vtl[g] = smem + 16384 + g*8192;
  //             pld[8][16][72] at smem + 32768 (18432B)
  __bf16 (*pld)[16][72] = reinterpret_cast<__bf16(*)[16][72]>(smem + 32768);

  const int h   = blockIdx.y;
  const int pi  = blockIdx.x;       // 0..15
  const int qbA = pi, qbB = 31 - pi;
  const int SS  = (qbB >> 1) + 1;   // super-steps (2 kts each)
  const int kvh = h >> 2;
  const int tid = threadIdx.x;
  const int l   = tid & 63;
  const int w   = tid >> 6;         // 0..7
  const int g   = tid >> 8;         // wave group / kt parity
  const int wg  = w & 3;            // row-group within q-tile
  const int l15 = l & 15;
  const int lg  = l >> 4;

  char* kldg = smem + g*8192;
  char* vtlg = smem + 16384 + g*8192;

  // staging geometry within the group's 256 threads (identical to R6)
  const int ts = tid & 255;
  const int j  = ts >> 2;
  const int c0 = (ts & 3) * 16;
  const int b0 = (j*128 + c0*2)      ^ ((j & 7) << 4);
  const int b1 = (j*128 + c0*2 + 16) ^ ((j & 7) << 4);
  const __bf16* ksrc = kbf  + (size_t)(g*64 + j)*(NKV_*HD_) + kvh*HD_ + c0;
  const __bf16* vsrc = vtbf + (size_t)(kvh*64 + j)*S_ + g*64 + c0;

  // Q fragments for both tiles
  bf16x8 qfA0, qfA1, qfB0, qfB1;
  {
    const __bf16* qa = qbf + (size_t)(qbA*64 + wg*16 + l15)*D_ + h*HD_ + lg*8;
    qfA0 = *reinterpret_cast<const bf16x8*>(qa);
    qfA1 = *reinterpret_cast<const bf16x8*>(qa + 32);
    const __bf16* qb = qbf + (size_t)(qbB*64 + wg*16 + l15)*D_ + h*HD_ + lg*8;
    qfB0 = *reinterpret_cast<const bf16x8*>(qb);
    qfB1 = *reinterpret_cast<const bf16x8*>(qb + 32);
  }

  f32x4 oA[4], oB[4];
#pragma unroll
  for (int nb = 0; nb < 4; ++nb) {
    oA[nb] = f32x4{0.f, 0.f, 0.f, 0.f};
    oB[nb] = f32x4{0.f, 0.f, 0.f, 0.f};
  }
  float mA[4] = {-1e30f, -1e30f, -1e30f, -1e30f};
  float lA[4] = {0.f, 0.f, 0.f, 0.f};
  float mB[4] = {-1e30f, -1e30f, -1e30f, -1e30f};
  float lB[4] = {0.f, 0.f, 0.f, 0.f};

  // prologue: prefetch this group's tile for st=0
  uint4 kr0 = reinterpret_cast<const uint4*>(ksrc)[0];
  uint4 kr1 = reinterpret_cast<const uint4*>(ksrc + 8)[0];
  uint4 vr0 = reinterpret_cast<const uint4*>(vsrc)[0];
  uint4 vr1 = reinterpret_cast<const uint4*>(vsrc + 8)[0];

  for (int st = 0; st < SS; ++st) {
    __syncthreads();
    *reinterpret_cast<uint4*>(kldg + b0) = kr0;
    *reinterpret_cast<uint4*>(kldg + b1) = kr1;
    *reinterpret_cast<uint4*>(vtlg + b0) = vr0;
    *reinterpret_cast<uint4*>(vtlg + b1) = vr1;
    __syncthreads();

    if (st + 1 < SS) {   // T14: next super-step's loads drain under compute
      const __bf16* kn = ksrc + (size_t)(st + 1)*128*(NKV_*HD_);
      const __bf16* vn = vsrc + (size_t)(st + 1)*128;
      kr0 = reinterpret_cast<const uint4*>(kn)[0];
      kr1 = reinterpret_cast<const uint4*>(kn + 8)[0];
      vr0 = reinterpret_cast<const uint4*>(vn)[0];
      vr1 = reinterpret_cast<const uint4*>(vn + 8)[0];
    }

    const int kt = 2*st + g;
    if (kt <= qbB) {
      f32x4 s_[4];
      qk_tile(kldg, qfB0, qfB1, s_, l15, lg);
      if (kt == qbB) mask_diag(s_, l15, lg, wg);
      softmax_pv(s_, mB, lB, oB, pld[w], vtlg, l15, lg);
    }
    if (kt <= qbA) {
      f32x4 s_[4];
      qk_tile(kldg, qfA0, qfA1, s_, l15, lg);
      if (kt == qbA) mask_diag(s_, l15, lg, wg);
      softmax_pv(s_, mA, lA, oA, pld[w], vtlg, l15, lg);
    }
  }

  // ---- merge parities (group1 -> LDS, group0 combines) ----
  float* ox = reinterpret_cast<float*>(smem);                  // stride-17 lanes
  float* ml = reinterpret_cast<float*>(smem + 34816);          // stride-9 lanes
  float* po = ox + wg*1088 + l*17;
  float* pm = ml + wg*576  + l*9;

  // phase B
  __syncthreads();
  if (g == 1) {
#pragma unroll
    for (int nb = 0; nb < 4; ++nb)
#pragma unroll
      for (int r = 0; r < 4; ++r) po[nb*4 + r] = oB[nb][r];
#pragma unroll
    for (int r = 0; r < 4; ++r) { pm[r] = mB[r]; pm[4 + r] = lB[r]; }
  }
  __syncthreads();
  if (g == 0) {
#pragma unroll
    for (int r = 0; r < 4; ++r) {
      const float m1 = pm[r], l1 = pm[4 + r];
      const float m = fmaxf(mB[r], m1);
      const float s0 = exp2f(mB[r] - m), s1 = exp2f(m1 - m);
      lB[r] = lB[r]*s0 + l1*s1;
#pragma unroll
      for (int nb = 0; nb < 4; ++nb)
        oB[nb][r] = oB[nb][r]*s0 + po[nb*4 + r]*s1;
      mB[r] = m;
    }
  }
  __syncthreads();
  // phase A
  if (g == 1) {
#pragma unroll
    for (int nb = 0; nb < 4; ++nb)
#pragma unroll
      for (int r = 0; r < 4; ++r) po[nb*4 + r] = oA[nb][r];
#pragma unroll
    for (int r = 0; r < 4; ++r) { pm[r] = mA[r]; pm[4 + r] = lA[r]; }
  }
  __syncthreads();
  if (g == 0) {
#pragma unroll
    for (int r = 0; r < 4; ++r) {
      const float m1 = pm[r], l1 = pm[4 + r];
      const float m = fmaxf(mA[r], m1);
      const float s0 = exp2f(mA[r] - m), s1 = exp2f(m1 - m);
      lA[r] = lA[r]*s0 + l1*s1;
#pragma unroll
      for (int nb = 0; nb < 4; ++nb)
        oA[nb][r] = oA[nb][r]*s0 + po[nb*4 + r]*s1;
      mA[r] = m;
    }
    // ---- epilogue (bf16 — only consumed by the wo GEMM) ----
#pragma unroll
    for (int nb = 0; nb < 4; ++nb) {
#pragma unroll
      for (int r = 0; r < 4; ++r) {
        const int rowA = qbA*64 + wg*16 + lg*4 + r;
        const int rowB = qbB*64 + wg*16 + lg*4 + r;
        ypre[(size_t)rowA*D_ + h*HD_ + nb*16 + l15] = (__bf16)(oA[nb][r] / lA[r]);
        ypre[(size_t)rowB*D_ + h*HD_ + nb*16 + l15] = (__bf16)(oB[nb][r] / lB[r]);
      }
    }
  }
}

// --------------------------------------------------------------------------
extern "C" void kernel_launch(void* const* d_in, const int* in_sizes, int n_in,
                              void* d_out, int out_size, void* d_ws, size_t ws_size,
                              hipStream_t stream) {
  (void)in_sizes; (void)n_in; (void)out_size;
  const float* hs   = (const float*)d_in[0];
  const float* fcos = (const float*)d_in[1];
  const float* fsin = (const float*)d_in[2];
  const float* wq = (const float*)d_in[4];
  const float* wk = (const float*)d_in[5];
  const float* wv = (const float*)d_in[6];
  const float* wo = (const float*)d_in[7];
  const float* qw = (const float*)d_in[8];
  const float* kw = (const float*)d_in[9];

  float* out = (float*)d_out;
  float* y   = out;                 // 2048*2048
  float* khT = out + 4194304;       // 32*64*2048
  float* vh  = out + 8388608;       // 32*2048*64

  __bf16* qbf   = (__bf16*)y;
  __bf16* kbf   = (__bf16*)((char*)y + 8*1024*1024);
  __bf16* vtbf  = (__bf16*)((char*)y + 10*1024*1024);
  __bf16* hs_bf = (__bf16*)khT;
  __bf16* wq_bf = (__bf16*)((char*)khT + 8*1024*1024);
  __bf16* wk_bf = (__bf16*)vh;
  __bf16* wv_bf = (__bf16*)((char*)vh + 2*1024*1024);

  const size_t need = (size_t)40 * 1024 * 1024;
  if (ws_size < need) return;
  char* ws = (char*)d_ws;
  float*  qp      = (float*)(ws);                    // 16MB
  float*  kp      = (float*)(ws + 16*1024*1024);     //  4MB
  float*  vp      = (float*)(ws + 20*1024*1024);     //  4MB
  __bf16* ypre_bf = (__bf16*)(ws + 24*1024*1024);    //  8MB
  __bf16* wo_bf   = (__bf16*)(ws + 32*1024*1024);    //  8MB

  // single fused conversion pass (5 regions)
  cvt_all<<<14336, 256, 0, stream>>>(hs, wq, wk, wv, wo,
                                     hs_bf, wq_bf, wk_bf, wv_bf, wo_bf);

  gemm_qkv<<<dim3(24, 16), 256, 0, stream>>>(hs_bf, wq_bf, wk_bf, wv_bf, qp, kp, vp);

  rope_norm_q<<<16384, 256, 0, stream>>>(qp, fcos, fsin, qw, qbf);
  rope_norm_k<<< 4096, 256, 0, stream>>>(kp, fcos, fsin, kw, kbf);

  transpose_khT<<<dim3(32, 8), 256, 0, stream>>>(kp, khT);
  transpose_v<<<dim3(32, 8), 256, 0, stream>>>(vp, vh, vtbf);

  // paired q-tiles + kt-parity wave split: 512 threads, 8 waves
  flash_attn_mfma<<<dim3(16, 32), 512, 0, stream>>>(qbf, kbf, vtbf, ypre_bf);

  gemm_wo<<<dim3(16, 16), 256, 0, stream>>>(ypre_bf, wo_bf, y);
}

// Round 11
// 171.658 us; speedup vs baseline: 1.1862x; 1.0940x over previous
//
#include <hip/hip_runtime.h>
#include <cstdint>
#include <cstddef>

#define S_   2048
#define D_   2048
#define NH_  32
#define NKV_ 8
#define HD_  64

using bf16x8 = __attribute__((ext_vector_type(8))) __bf16;
using f32x4  = __attribute__((ext_vector_type(4))) float;

#define AS_GLOBAL(p) (const __attribute__((address_space(1))) void*)(p)
#define AS_LDS(p)    (__attribute__((address_space(3))) void*)(p)

// ---------------- fused f32 -> bf16 bulk convert (5 regions) --------------
__global__ __launch_bounds__(256) void cvt_all(
    const float* __restrict__ hs, const float* __restrict__ wq,
    const float* __restrict__ wk, const float* __restrict__ wv,
    const float* __restrict__ wo,
    __bf16* __restrict__ hs_bf, __bf16* __restrict__ wq_bf,
    __bf16* __restrict__ wk_bf, __bf16* __restrict__ wv_bf,
    __bf16* __restrict__ wo_bf) {
  int i = blockIdx.x * 256 + threadIdx.x;   // float4 index; total 3670016
  const float* src; __bf16* dst; int base;
  if (i < 1048576)      { src = hs; dst = hs_bf; base = 0; }
  else if (i < 2097152) { src = wq; dst = wq_bf; base = 1048576; }
  else if (i < 2359296) { src = wk; dst = wk_bf; base = 2097152; }
  else if (i < 2621440) { src = wv; dst = wv_bf; base = 2359296; }
  else                  { src = wo; dst = wo_bf; base = 2621440; }
  i -= base;
  const float4 v = reinterpret_cast<const float4*>(src)[i];
  __bf16 t[4] = {(__bf16)v.x, (__bf16)v.y, (__bf16)v.z, (__bf16)v.w};
  reinterpret_cast<uint2*>(dst)[i] = *reinterpret_cast<uint2*>(t);
}

// ---------------- bf16 MFMA GEMM core: C[M][N] = A[M][K] * B[N][K]^T ------
__device__ __forceinline__ void gemm_tile_128(
    const __bf16* __restrict__ A, const __bf16* __restrict__ B,
    float* __restrict__ C, int K, int N, int m0, int n0) {
  __shared__ __align__(16) char ldsA[16384];
  __shared__ __align__(16) char ldsB[16384];
  const int tid = threadIdx.x;
  const int l = tid & 63;
  const int w = tid >> 6;
  const int l15 = l & 15, lg = l >> 4;
  const int wm = w >> 1, wn = w & 1;

  f32x4 acc[4][4] = {};

  const int srow   = tid >> 3;
  const int schunk = (tid & 7) ^ (srow & 7);
  const __bf16* gA = A + (size_t)(m0 + srow) * K + schunk * 8;
  const __bf16* gB = B + (size_t)(n0 + srow) * K + schunk * 8;
  const int ldst = tid * 16;

  for (int k0 = 0; k0 < K; k0 += 64) {
    __syncthreads();
#pragma unroll
    for (int i = 0; i < 4; ++i) {
      __builtin_amdgcn_global_load_lds(AS_GLOBAL(gA + (size_t)i*32*K + k0),
                                       AS_LDS(ldsA + i*4096 + ldst), 16, 0, 0);
      __builtin_amdgcn_global_load_lds(AS_GLOBAL(gB + (size_t)i*32*K + k0),
                                       AS_LDS(ldsB + i*4096 + ldst), 16, 0, 0);
    }
    __syncthreads();

    bf16x8 af[4][2], bfr[4][2];
#pragma unroll
    for (int f = 0; f < 4; ++f) {
      const int arow = wm*64 + f*16 + l15;
      const int brow = wn*64 + f*16 + l15;
#pragma unroll
      for (int ks = 0; ks < 2; ++ks) {
        af[f][ks] = *reinterpret_cast<const bf16x8*>(
            ldsA + arow*128 + (((ks*4 + lg) ^ (arow & 7)) << 4));
        bfr[f][ks] = *reinterpret_cast<const bf16x8*>(
            ldsB + brow*128 + (((ks*4 + lg) ^ (brow & 7)) << 4));
      }
    }
#pragma unroll
    for (int mf = 0; mf < 4; ++mf)
#pragma unroll
      for (int nf = 0; nf < 4; ++nf) {
        acc[mf][nf] = __builtin_amdgcn_mfma_f32_16x16x32_bf16(
            af[mf][0], bfr[nf][0], acc[mf][nf], 0, 0, 0);
        acc[mf][nf] = __builtin_amdgcn_mfma_f32_16x16x32_bf16(
            af[mf][1], bfr[nf][1], acc[mf][nf], 0, 0, 0);
      }
  }

#pragma unroll
  for (int mf = 0; mf < 4; ++mf)
#pragma unroll
    for (int nf = 0; nf < 4; ++nf)
#pragma unroll
      for (int r = 0; r < 4; ++r)
        C[(size_t)(m0 + wm*64 + mf*16 + lg*4 + r) * N + n0 + wn*64 + nf*16 + l15]
            = acc[mf][nf][r];
}

// fused Q/K/V projection: grid.x 0..15 -> wq tiles, 16..19 -> wk, 20..23 -> wv
__global__ __launch_bounds__(256) void gemm_qkv(
    const __bf16* __restrict__ hs,
    const __bf16* __restrict__ wq, const __bf16* __restrict__ wk,
    const __bf16* __restrict__ wv,
    float* __restrict__ qp, float* __restrict__ kp, float* __restrict__ vp) {
  const int bx = blockIdx.x;
  const __bf16* Bm; float* Cm; int N, n0;
  if (bx < 16)      { Bm = wq; Cm = qp; N = 2048; n0 = bx * 128; }
  else if (bx < 20) { Bm = wk; Cm = kp; N = 512;  n0 = (bx - 16) * 128; }
  else              { Bm = wv; Cm = vp; N = 512;  n0 = (bx - 20) * 128; }
  gemm_tile_128(hs, Bm, Cm, 2048, N, blockIdx.y * 128, n0);
}

__global__ __launch_bounds__(256) void gemm_wo(
    const __bf16* __restrict__ ypre, const __bf16* __restrict__ wo,
    float* __restrict__ y) {
  gemm_tile_128(ypre, wo, y, 2048, 2048, blockIdx.y * 128, blockIdx.x * 128);
}

// ---------------- RoPE + RMSNorm, q variant -------------------------------
// fold (1/SCALE)*log2(e) into q so flash softmax runs in exp2 domain
__global__ __launch_bounds__(256) void rope_norm_q(
    const float* __restrict__ q, const float* __restrict__ cosT,
    const float* __restrict__ sinT, const float* __restrict__ w,
    __bf16* __restrict__ qbf) {
  const int wid  = (int)((blockIdx.x * 256 + threadIdx.x) >> 6);
  const int lane = threadIdx.x & 63;
  const int s = wid >> 5;
  const int h = wid & 31;
  const size_t idx = (size_t)s*D_ + h*HD_ + lane;
  float val = q[idx];
  const float c  = cosT[s*32 + (lane >> 1)];
  const float sn = sinT[s*32 + (lane >> 1)];
  const float partner = __shfl_xor(val, 1);
  const float ro = (lane & 1) ? fmaf(partner, sn, val*c)
                              : fmaf(val, c, -partner*sn);
  float ssq = ro * ro;
#pragma unroll
  for (int off = 32; off >= 1; off >>= 1) ssq += __shfl_xor(ssq, off);
  const float rinv = rsqrtf(ssq * (1.0f/64.0f) + 1e-5f);
  qbf[idx] = (__bf16)(ro * rinv * w[lane] * 0.180336880111120426f);
}

// ---------------- RoPE + RMSNorm, k variant: kp in place + kbf(bf16) -----
__global__ __launch_bounds__(256) void rope_norm_k(
    float* __restrict__ k, const float* __restrict__ cosT,
    const float* __restrict__ sinT, const float* __restrict__ w,
    __bf16* __restrict__ kbf) {
  const int wid  = (int)((blockIdx.x * 256 + threadIdx.x) >> 6);
  const int lane = threadIdx.x & 63;
  const int s   = wid >> 3;
  const int kvh = wid & 7;
  const size_t idx = (size_t)s*(NKV_*HD_) + kvh*HD_ + lane;
  float val = k[idx];
  const float c  = cosT[s*32 + (lane >> 1)];
  const float sn = sinT[s*32 + (lane >> 1)];
  const float partner = __shfl_xor(val, 1);
  const float ro = (lane & 1) ? fmaf(partner, sn, val*c)
                              : fmaf(val, c, -partner*sn);
  float ssq = ro * ro;
#pragma unroll
  for (int off = 32; off >= 1; off >>= 1) ssq += __shfl_xor(ssq, off);
  const float rinv = rsqrtf(ssq * (1.0f/64.0f) + 1e-5f);
  const float res = ro * rinv * w[lane];
  k[idx] = res;
  kbf[idx] = (__bf16)res;
}

// ---------------- khT output: khT[h][d][s] = k_post[kvh=h/4][s][d] --------
__global__ __launch_bounds__(256) void transpose_khT(
    const float* __restrict__ kpost, float* __restrict__ khT) {
  __shared__ float tl[64][68];
  const int s0  = blockIdx.x * 64;
  const int kvh = blockIdx.y;
  const int t = threadIdx.x;
  {
    const int d0 = (t & 15) * 4;
    const int sl = t >> 4;
#pragma unroll
    for (int rep = 0; rep < 4; ++rep) {
      const int srow = sl + rep*16;
      float4 v = *reinterpret_cast<const float4*>(
          &kpost[(size_t)(s0 + srow)*(NKV_*HD_) + kvh*HD_ + d0]);
      tl[d0+0][srow]=v.x; tl[d0+1][srow]=v.y; tl[d0+2][srow]=v.z; tl[d0+3][srow]=v.w;
    }
  }
  __syncthreads();
  {
    const int d  = t >> 2;
    const int s4 = (t & 3) * 16;
#pragma unroll
    for (int c = 0; c < 4; ++c) {
      float4 v;
      v.x = tl[d][s4+c*4+0]; v.y = tl[d][s4+c*4+1];
      v.z = tl[d][s4+c*4+2]; v.w = tl[d][s4+c*4+3];
#pragma unroll
      for (int r = 0; r < 4; ++r) {
        *reinterpret_cast<float4*>(
            &khT[((size_t)(kvh*4 + r)*HD_ + d)*S_ + s0 + s4 + c*4]) = v;
      }
    }
  }
}

// ---------------- V: vh output (f32, replicated) + vT global (bf16) -------
__global__ __launch_bounds__(256) void transpose_v(
    const float* __restrict__ vp, float* __restrict__ vh,
    __bf16* __restrict__ vtbf) {
  __shared__ float tl[64][68];
  const int s0  = blockIdx.x * 64;
  const int kvh = blockIdx.y;
  const int t = threadIdx.x;
  const int srow = t >> 2, dc = (t & 3) * 16;
  const float* src = &vp[(size_t)(s0 + srow)*(NKV_*HD_) + kvh*HD_ + dc];
  float4 a = reinterpret_cast<const float4*>(src)[0];
  float4 b = reinterpret_cast<const float4*>(src)[1];
  float4 c = reinterpret_cast<const float4*>(src)[2];
  float4 d = reinterpret_cast<const float4*>(src)[3];
  *reinterpret_cast<float4*>(&tl[srow][dc])      = a;
  *reinterpret_cast<float4*>(&tl[srow][dc + 4])  = b;
  *reinterpret_cast<float4*>(&tl[srow][dc + 8])  = c;
  *reinterpret_cast<float4*>(&tl[srow][dc + 12]) = d;
#pragma unroll
  for (int r = 0; r < 4; ++r) {
    float* dst = &vh[((size_t)(kvh*4 + r)*S_ + s0 + srow)*HD_ + dc];
    reinterpret_cast<float4*>(dst)[0] = a;
    reinterpret_cast<float4*>(dst)[1] = b;
    reinterpret_cast<float4*>(dst)[2] = c;
    reinterpret_cast<float4*>(dst)[3] = d;
  }
  __syncthreads();
  const int dr = t >> 2, sc = (t & 3) * 16;
  __bf16 vals[16];
#pragma unroll
  for (int i = 0; i < 16; ++i) vals[i] = (__bf16)tl[sc + i][dr];
  uint4* dst = reinterpret_cast<uint4*>(&vtbf[((size_t)(kvh*64 + dr))*S_ + s0 + sc]);
  dst[0] = reinterpret_cast<uint4*>(vals)[0];
  dst[1] = reinterpret_cast<uint4*>(vals)[1];
}

// ---------------- flash helpers (swapped-operand T12 form) ----------------
__device__ __forceinline__ uint pack2bf(float a, float b) {
  __bf16 x = (__bf16)a, y = (__bf16)b;
  const uint ux = (uint)*reinterpret_cast<ushort*>(&x);
  const uint uy = (uint)*reinterpret_cast<ushort*>(&y);
  return ux | (uy << 16);
}

// S^T = K * Q^T : lane holds S[key = nb*16+lg*4+r][qrow = l15]
__device__ __forceinline__ void qk_tile_T(
    const char* kldh, bf16x8 qf0, bf16x8 qf1, f32x4 (&s_)[4],
    int l15, int lg) {
  __builtin_amdgcn_s_setprio(1);
#pragma unroll
  for (int nb = 0; nb < 4; ++nb) {
    const int row = nb*16 + l15;                 // key row in kld
    const int bc  = lg*16;
    const bf16x8 kb0 = *reinterpret_cast<const bf16x8*>(
        kldh + row*128 + ((bc)      ^ ((row & 7) << 4)));
    const bf16x8 kb1 = *reinterpret_cast<const bf16x8*>(
        kldh + row*128 + ((bc + 64) ^ ((row & 7) << 4)));
    f32x4 t = f32x4{0.f, 0.f, 0.f, 0.f};
    t = __builtin_amdgcn_mfma_f32_16x16x32_bf16(kb0, qf0, t, 0, 0, 0);  // swapped
    t = __builtin_amdgcn_mfma_f32_16x16x32_bf16(kb1, qf1, t, 0, 0, 0);
    s_[nb] = t;
  }
  __builtin_amdgcn_s_setprio(0);
}

// exp2-domain softmax with lane-local rows (m_, l_ scalars) + swapped PV.
// pldw: per-wave [16 qrow][64 key] bf16, kld-style XOR swizzle.
__device__ __forceinline__ void softmax_pv_T(
    f32x4 (&s_)[4], float& m_, float& l_, f32x4 (&o_)[4],
    char* pldw, const char* vbase, int l15, int lg) {
  // row max: in-register over 16 + 2 shfl hops (lanes sharing l15)
  float mx = fmaxf(fmaxf(s_[0][0], s_[0][1]), fmaxf(s_[0][2], s_[0][3]));
#pragma unroll
  for (int nb = 1; nb < 4; ++nb) {
    mx = fmaxf(mx, fmaxf(fmaxf(s_[nb][0], s_[nb][1]),
                         fmaxf(s_[nb][2], s_[nb][3])));
  }
  mx = fmaxf(mx, __shfl_xor(mx, 16));
  mx = fmaxf(mx, __shfl_xor(mx, 32));
  const float mnew = fmaxf(m_, mx);
  const float scl = exp2f(m_ - mnew);
  m_ = mnew;

  const int swz = (l15 & 7) << 4;
  float ls = 0.f;
#pragma unroll
  for (int nb = 0; nb < 4; ++nb) {
    float p0 = exp2f(s_[nb][0] - mnew);
    float p1 = exp2f(s_[nb][1] - mnew);
    float p2 = exp2f(s_[nb][2] - mnew);
    float p3 = exp2f(s_[nb][3] - mnew);
    ls += (p0 + p1) + (p2 + p3);
    // P^T store: row l15 (qrow), elems nb*16 + lg*4 + {0..3} -> two b32
    *reinterpret_cast<uint*>(pldw + ((l15*128 + nb*32 + lg*8)     ^ swz)) = pack2bf(p0, p1);
    *reinterpret_cast<uint*>(pldw + ((l15*128 + nb*32 + lg*8 + 4) ^ swz)) = pack2bf(p2, p3);
  }
  ls += __shfl_xor(ls, 16);
  ls += __shfl_xor(ls, 32);
  l_ = l_*scl + ls;
#pragma unroll
  for (int nb = 0; nb < 4; ++nb) {
    o_[nb][0] *= scl; o_[nb][1] *= scl; o_[nb][2] *= scl; o_[nb][3] *= scl;
  }

  // P^T fragments (B operand): row l15, keys lg*8.. and +32
  const bf16x8 pb0 = *reinterpret_cast<const bf16x8*>(
      pldw + ((l15*128 + lg*16)      ^ swz));
  const bf16x8 pb1 = *reinterpret_cast<const bf16x8*>(
      pldw + ((l15*128 + lg*16 + 64) ^ swz));

  __builtin_amdgcn_s_setprio(1);
#pragma unroll
  for (int nb = 0; nb < 4; ++nb) {
    const int row = nb*16 + l15;                 // d row in vtl
    const int bc  = lg*16;
    const bf16x8 v0 = *reinterpret_cast<const bf16x8*>(
        vbase + row*128 + ((bc)      ^ ((row & 7) << 4)));
    const bf16x8 v1 = *reinterpret_cast<const bf16x8*>(
        vbase + row*128 + ((bc + 64) ^ ((row & 7) << 4)));
    f32x4 t = o_[nb];
    t = __builtin_amdgcn_mfma_f32_16x16x32_bf16(v0, pb0, t, 0, 0, 0);  // O^T
    t = __builtin_amdgcn_mfma_f32_16x16x32_bf16(v1, pb1, t, 0, 0, 0);
    o_[nb] = t;
  }
  __builtin_amdgcn_s_setprio(0);
}

// causal mask in S^T layout: key = nb*16+lg*4+r, qrow = wg*16 + l15
__device__ __forceinline__ void mask_diag_T(f32x4 (&s_)[4], int l15, int lg, int wg) {
  const int qrow = wg*16 + l15;
#pragma unroll
  for (int nb = 0; nb < 4; ++nb)
#pragma unroll
    for (int r = 0; r < 4; ++r)
      if (nb*16 + lg*4 + r > qrow) s_[nb][r] = -1e30f;
}

// ---------------- causal flash attention, paired q-tiles, kt-parity split -
// 512 threads = 8 waves; group g handles kt = 2*st + g for q-tiles A=i, B=31-i.
// Swapped QK^T (T12): softmax rows are lane-local (qrow = wg*16 + l15).
__global__ __launch_bounds__(512, 4) void flash_attn_mfma(
    const __bf16* __restrict__ qbf, const __bf16* __restrict__ kbf,
    const __bf16* __restrict__ vtbf, __bf16* __restrict__ ypre) {
  __shared__ __align__(16) char smem[49152];
  // kld[g] = smem + g*8192 ; vtl[g] = smem + 16384 + g*8192 ;
  // pld[w]  = smem + 32768 + w*2048   (per-wave [16][64] bf16, XOR-swizzled)

  const int h   = blockIdx.y;
  const int pi  = blockIdx.x;       // 0..15
  const int qbA = pi, qbB = 31 - pi;
  const int SS  = (qbB >> 1) + 1;   // super-steps (2 kts each)
  const int kvh = h >> 2;
  const int tid = threadIdx.x;
  const int l   = tid & 63;
  const int w   = tid >> 6;         // 0..7
  const int g   = tid >> 8;         // kt parity group
  const int wg  = w & 3;            // row-group within q-tile
  const int l15 = l & 15;
  const int lg  = l >> 4;

  char* kldg = smem + g*8192;
  char* vtlg = smem + 16384 + g*8192;
  char* pldw = smem + 32768 + w*2048;

  // staging geometry within the group's 256 threads
  const int ts = tid & 255;
  const int j  = ts >> 2;
  const int c0 = (ts & 3) * 16;
  const int b0 = (j*128 + c0*2)      ^ ((j & 7) << 4);
  const int b1 = (j*128 + c0*2 + 16) ^ ((j & 7) << 4);
  const __bf16* ksrc = kbf  + (size_t)(g*64 + j)*(NKV_*HD_) + kvh*HD_ + c0;
  const __bf16* vsrc = vtbf + (size_t)(kvh*64 + j)*S_ + g*64 + c0;

  // Q fragments for both tiles (rows wg*16 + l15)
  bf16x8 qfA0, qfA1, qfB0, qfB1;
  {
    const __bf16* qa = qbf + (size_t)(qbA*64 + wg*16 + l15)*D_ + h*HD_ + lg*8;
    qfA0 = *reinterpret_cast<const bf16x8*>(qa);
    qfA1 = *reinterpret_cast<const bf16x8*>(qa + 32);
    const __bf16* qb = qbf + (size_t)(qbB*64 + wg*16 + l15)*D_ + h*HD_ + lg*8;
    qfB0 = *reinterpret_cast<const bf16x8*>(qb);
    qfB1 = *reinterpret_cast<const bf16x8*>(qb + 32);
  }

  f32x4 oA[4], oB[4];
#pragma unroll
  for (int nb = 0; nb < 4; ++nb) {
    oA[nb] = f32x4{0.f, 0.f, 0.f, 0.f};
    oB[nb] = f32x4{0.f, 0.f, 0.f, 0.f};
  }
  float mA = -1e30f, lA = 0.f, mB = -1e30f, lB = 0.f;

  // prologue: prefetch this group's tile for st=0
  uint4 kr0 = reinterpret_cast<const uint4*>(ksrc)[0];
  uint4 kr1 = reinterpret_cast<const uint4*>(ksrc + 8)[0];
  uint4 vr0 = reinterpret_cast<const uint4*>(vsrc)[0];
  uint4 vr1 = reinterpret_cast<const uint4*>(vsrc + 8)[0];

  for (int st = 0; st < SS; ++st) {
    __syncthreads();
    *reinterpret_cast<uint4*>(kldg + b0) = kr0;
    *reinterpret_cast<uint4*>(kldg + b1) = kr1;
    *reinterpret_cast<uint4*>(vtlg + b0) = vr0;
    *reinterpret_cast<uint4*>(vtlg + b1) = vr1;
    __syncthreads();

    if (st + 1 < SS) {   // T14: next super-step's loads drain under compute
      const __bf16* kn = ksrc + (size_t)(st + 1)*128*(NKV_*HD_);
      const __bf16* vn = vsrc + (size_t)(st + 1)*128;
      kr0 = reinterpret_cast<const uint4*>(kn)[0];
      kr1 = reinterpret_cast<const uint4*>(kn + 8)[0];
      vr0 = reinterpret_cast<const uint4*>(vn)[0];
      vr1 = reinterpret_cast<const uint4*>(vn + 8)[0];
    }

    const int kt = 2*st + g;
    if (kt <= qbB) {
      f32x4 s_[4];
      qk_tile_T(kldg, qfB0, qfB1, s_, l15, lg);
      if (kt == qbB) mask_diag_T(s_, l15, lg, wg);
      softmax_pv_T(s_, mB, lB, oB, pldw, vtlg, l15, lg);
    }
    if (kt <= qbA) {
      f32x4 s_[4];
      qk_tile_T(kldg, qfA0, qfA1, s_, l15, lg);
      if (kt == qbA) mask_diag_T(s_, l15, lg, wg);
      softmax_pv_T(s_, mA, lA, oA, pldw, vtlg, l15, lg);
    }
  }

  // ---- merge parities (group1 -> LDS, group0 combines) ----
  float* ox = reinterpret_cast<float*>(smem);                 // 256 lanes x 17
  float* ml = reinterpret_cast<float*>(smem + 20480);         // 256 lanes x 9
  float* po = ox + (wg*64 + l)*17;
  float* pm = ml + (wg*64 + l)*9;

  // phase B
  __syncthreads();
  if (g == 1) {
#pragma unroll
    for (int nb = 0; nb < 4; ++nb)
#pragma unroll
      for (int r = 0; r < 4; ++r) po[nb*4 + r] = oB[nb][r];
    pm[0] = mB; pm[1] = lB;
  }
  __syncthreads();
  if (g == 0) {
    const float m1 = pm[0], l1 = pm[1];
    const float m = fmaxf(mB, m1);
    const float s0 = exp2f(mB - m), s1 = exp2f(m1 - m);
    lB = lB*s0 + l1*s1;
#pragma unroll
    for (int nb = 0; nb < 4; ++nb)
#pragma unroll
      for (int r = 0; r < 4; ++r)
        oB[nb][r] = oB[nb][r]*s0 + po[nb*4 + r]*s1;
  }
  __syncthreads();
  // phase A
  if (g == 1) {
#pragma unroll
    for (int nb = 0; nb < 4; ++nb)
#pragma unroll
      for (int r = 0; r < 4; ++r) po[nb*4 + r] = oA[nb][r];
    pm[0] = mA; pm[1] = lA;
  }
  __syncthreads();
  if (g == 0) {
    const float m1 = pm[0], l1 = pm[1];
    const float m = fmaxf(mA, m1);
    const float s0 = exp2f(mA - m), s1 = exp2f(m1 - m);
    lA = lA*s0 + l1*s1;
#pragma unroll
    for (int nb = 0; nb < 4; ++nb)
#pragma unroll
      for (int r = 0; r < 4; ++r)
        oA[nb][r] = oA[nb][r]*s0 + po[nb*4 + r]*s1;

    // ---- epilogue: lane owns one q-row per tile; 4x 8B packed stores each
    const float rlA = 1.0f / lA, rlB = 1.0f / lB;
    const size_t rowA = (size_t)(qbA*64 + wg*16 + l15)*D_ + h*HD_;
    const size_t rowB = (size_t)(qbB*64 + wg*16 + l15)*D_ + h*HD_;
#pragma unroll
    for (int nb = 0; nb < 4; ++nb) {
      uint2 pa, pb;
      pa.x = pack2bf(oA[nb][0]*rlA, oA[nb][1]*rlA);
      pa.y = pack2bf(oA[nb][2]*rlA, oA[nb][3]*rlA);
      pb.x = pack2bf(oB[nb][0]*rlB, oB[nb][1]*rlB);
      pb.y = pack2bf(oB[nb][2]*rlB, oB[nb][3]*rlB);
      *reinterpret_cast<uint2*>(&ypre[rowA + nb*16 + lg*4]) = pa;
      *reinterpret_cast<uint2*>(&ypre[rowB + nb*16 + lg*4]) = pb;
    }
  }
}

// --------------------------------------------------------------------------
extern "C" void kernel_launch(void* const* d_in, const int* in_sizes, int n_in,
                              void* d_out, int out_size, void* d_ws, size_t ws_size,
                              hipStream_t stream) {
  (void)in_sizes; (void)n_in; (void)out_size;
  const float* hs   = (const float*)d_in[0];
  const float* fcos = (const float*)d_in[1];
  const float* fsin = (const float*)d_in[2];
  const float* wq = (const float*)d_in[4];
  const float* wk = (const float*)d_in[5];
  const float* wv = (const float*)d_in[6];
  const float* wo = (const float*)d_in[7];
  const float* qw = (const float*)d_in[8];
  const float* kw = (const float*)d_in[9];

  float* out = (float*)d_out;
  float* y   = out;                 // 2048*2048
  float* khT = out + 4194304;       // 32*64*2048
  float* vh  = out + 8388608;       // 32*2048*64

  __bf16* qbf   = (__bf16*)y;
  __bf16* kbf   = (__bf16*)((char*)y + 8*1024*1024);
  __bf16* vtbf  = (__bf16*)((char*)y + 10*1024*1024);
  __bf16* hs_bf = (__bf16*)khT;
  __bf16* wq_bf = (__bf16*)((char*)khT + 8*1024*1024);
  __bf16* wk_bf = (__bf16*)vh;
  __bf16* wv_bf = (__bf16*)((char*)vh + 2*1024*1024);

  const size_t need = (size_t)40 * 1024 * 1024;
  if (ws_size < need) return;
  char* ws = (char*)d_ws;
  float*  qp      = (float*)(ws);                    // 16MB
  float*  kp      = (float*)(ws + 16*1024*1024);     //  4MB
  float*  vp      = (float*)(ws + 20*1024*1024);     //  4MB
  __bf16* ypre_bf = (__bf16*)(ws + 24*1024*1024);    //  8MB
  __bf16* wo_bf   = (__bf16*)(ws + 32*1024*1024);    //  8MB

  cvt_all<<<14336, 256, 0, stream>>>(hs, wq, wk, wv, wo,
                                     hs_bf, wq_bf, wk_bf, wv_bf, wo_bf);

  gemm_qkv<<<dim3(24, 16), 256, 0, stream>>>(hs_bf, wq_bf, wk_bf, wv_bf, qp, kp, vp);

  rope_norm_q<<<16384, 256, 0, stream>>>(qp, fcos, fsin, qw, qbf);
  rope_norm_k<<< 4096, 256, 0, stream>>>(kp, fcos, fsin, kw, kbf);

  transpose_khT<<<dim3(32, 8), 256, 0, stream>>>(kp, khT);
  transpose_v<<<dim3(32, 8), 256, 0, stream>>>(vp, vh, vtbf);

  flash_attn_mfma<<<dim3(16, 32), 512, 0, stream>>>(qbf, kbf, vtbf, ypre_bf);

  gemm_wo<<<dim3(16, 16), 256, 0, stream>>>(ypre_bf, wo_bf, y);
}

// Round 12
// 159.348 us; speedup vs baseline: 1.2779x; 1.0772x over previous
//
#include <hip/hip_runtime.h>
#include <cstdint>
#include <cstddef>

#define S_   2048
#define D_   2048
#define NH_  32
#define NKV_ 8
#define HD_  64

using bf16x8 = __attribute__((ext_vector_type(8))) __bf16;
using f32x4  = __attribute__((ext_vector_type(4))) float;

#define AS_GLOBAL(p) (const __attribute__((address_space(1))) void*)(p)
#define AS_LDS(p)    (__attribute__((address_space(3))) void*)(p)

// ---------------- fused f32 -> bf16 bulk convert (5 regions) --------------
__global__ __launch_bounds__(256) void cvt_all(
    const float* __restrict__ hs, const float* __restrict__ wq,
    const float* __restrict__ wk, const float* __restrict__ wv,
    const float* __restrict__ wo,
    __bf16* __restrict__ hs_bf, __bf16* __restrict__ wq_bf,
    __bf16* __restrict__ wk_bf, __bf16* __restrict__ wv_bf,
    __bf16* __restrict__ wo_bf) {
  int i = blockIdx.x * 256 + threadIdx.x;   // float4 index; total 3670016
  const float* src; __bf16* dst; int base;
  if (i < 1048576)      { src = hs; dst = hs_bf; base = 0; }
  else if (i < 2097152) { src = wq; dst = wq_bf; base = 1048576; }
  else if (i < 2359296) { src = wk; dst = wk_bf; base = 2097152; }
  else if (i < 2621440) { src = wv; dst = wv_bf; base = 2359296; }
  else                  { src = wo; dst = wo_bf; base = 2621440; }
  i -= base;
  const float4 v = reinterpret_cast<const float4*>(src)[i];
  __bf16 t[4] = {(__bf16)v.x, (__bf16)v.y, (__bf16)v.z, (__bf16)v.w};
  reinterpret_cast<uint2*>(dst)[i] = *reinterpret_cast<uint2*>(t);
}

// ---------------- bf16 MFMA GEMM core: C[M][N] = A[M][K] * B[N][K]^T ------
// 128x128 tile, BK=64, 4 waves. T3-minimum 2-phase pipeline: double-buffered
// LDS, STAGE(t+1) issued BEFORE compute(t), one barrier per K-step so the
// global->LDS latency drains under the MFMA phase (critical at 1 block/CU).
__device__ __forceinline__ void gemm_tile_128(
    const __bf16* __restrict__ A, const __bf16* __restrict__ B,
    float* __restrict__ C, int K, int N, int m0, int n0) {
  __shared__ __align__(16) char lds[2][32768];   // [buf][A 16K | B 16K]
  const int tid = threadIdx.x;
  const int l = tid & 63;
  const int w = tid >> 6;
  const int l15 = l & 15, lg = l >> 4;
  const int wm = w >> 1, wn = w & 1;

  f32x4 acc[4][4] = {};

  const int srow   = tid >> 3;
  const int schunk = (tid & 7) ^ (srow & 7);
  const __bf16* gA = A + (size_t)(m0 + srow) * K + schunk * 8;
  const __bf16* gB = B + (size_t)(n0 + srow) * K + schunk * 8;
  const int ldst = tid * 16;
  const int nt = K >> 6;

  // prologue: stage tile 0 into buf 0
#pragma unroll
  for (int i = 0; i < 4; ++i) {
    __builtin_amdgcn_global_load_lds(AS_GLOBAL(gA + (size_t)i*32*K),
                                     AS_LDS(&lds[0][i*4096 + ldst]), 16, 0, 0);
    __builtin_amdgcn_global_load_lds(AS_GLOBAL(gB + (size_t)i*32*K),
                                     AS_LDS(&lds[0][16384 + i*4096 + ldst]), 16, 0, 0);
  }
  __syncthreads();   // compiler drains vmcnt(0) before barrier

  int cur = 0;
  for (int t = 0; t < nt; ++t) {
    // issue next tile's loads first; they drain under this tile's MFMA
    if (t + 1 < nt) {
      const int k0 = (t + 1) * 64;
      char* dA = &lds[cur ^ 1][0];
      char* dB = &lds[cur ^ 1][16384];
#pragma unroll
      for (int i = 0; i < 4; ++i) {
        __builtin_amdgcn_global_load_lds(AS_GLOBAL(gA + (size_t)i*32*K + k0),
                                         AS_LDS(dA + i*4096 + ldst), 16, 0, 0);
        __builtin_amdgcn_global_load_lds(AS_GLOBAL(gB + (size_t)i*32*K + k0),
                                         AS_LDS(dB + i*4096 + ldst), 16, 0, 0);
      }
    }

    const char* ldsA = &lds[cur][0];
    const char* ldsB = &lds[cur][16384];
    bf16x8 af[4][2], bfr[4][2];
#pragma unroll
    for (int f = 0; f < 4; ++f) {
      const int arow = wm*64 + f*16 + l15;
      const int brow = wn*64 + f*16 + l15;
#pragma unroll
      for (int ks = 0; ks < 2; ++ks) {
        af[f][ks] = *reinterpret_cast<const bf16x8*>(
            ldsA + arow*128 + (((ks*4 + lg) ^ (arow & 7)) << 4));
        bfr[f][ks] = *reinterpret_cast<const bf16x8*>(
            ldsB + brow*128 + (((ks*4 + lg) ^ (brow & 7)) << 4));
      }
    }
#pragma unroll
    for (int mf = 0; mf < 4; ++mf)
#pragma unroll
      for (int nf = 0; nf < 4; ++nf) {
        acc[mf][nf] = __builtin_amdgcn_mfma_f32_16x16x32_bf16(
            af[mf][0], bfr[nf][0], acc[mf][nf], 0, 0, 0);
        acc[mf][nf] = __builtin_amdgcn_mfma_f32_16x16x32_bf16(
            af[mf][1], bfr[nf][1], acc[mf][nf], 0, 0, 0);
      }

    __syncthreads();   // drains vmcnt(0): next buffer ready, reads complete
    cur ^= 1;
  }

#pragma unroll
  for (int mf = 0; mf < 4; ++mf)
#pragma unroll
    for (int nf = 0; nf < 4; ++nf)
#pragma unroll
      for (int r = 0; r < 4; ++r)
        C[(size_t)(m0 + wm*64 + mf*16 + lg*4 + r) * N + n0 + wn*64 + nf*16 + l15]
            = acc[mf][nf][r];
}

// fused Q/K/V projection: grid.x 0..15 -> wq tiles, 16..19 -> wk, 20..23 -> wv
__global__ __launch_bounds__(256) void gemm_qkv(
    const __bf16* __restrict__ hs,
    const __bf16* __restrict__ wq, const __bf16* __restrict__ wk,
    const __bf16* __restrict__ wv,
    float* __restrict__ qp, float* __restrict__ kp, float* __restrict__ vp) {
  const int bx = blockIdx.x;
  const __bf16* Bm; float* Cm; int N, n0;
  if (bx < 16)      { Bm = wq; Cm = qp; N = 2048; n0 = bx * 128; }
  else if (bx < 20) { Bm = wk; Cm = kp; N = 512;  n0 = (bx - 16) * 128; }
  else              { Bm = wv; Cm = vp; N = 512;  n0 = (bx - 20) * 128; }
  gemm_tile_128(hs, Bm, Cm, 2048, N, blockIdx.y * 128, n0);
}

__global__ __launch_bounds__(256) void gemm_wo(
    const __bf16* __restrict__ ypre, const __bf16* __restrict__ wo,
    float* __restrict__ y) {
  gemm_tile_128(ypre, wo, y, 2048, 2048, blockIdx.y * 128, blockIdx.x * 128);
}

// ---------------- RoPE + RMSNorm, q variant -------------------------------
// fold (1/SCALE)*log2(e) into q so flash softmax runs in exp2 domain
__global__ __launch_bounds__(256) void rope_norm_q(
    const float* __restrict__ q, const float* __restrict__ cosT,
    const float* __restrict__ sinT, const float* __restrict__ w,
    __bf16* __restrict__ qbf) {
  const int wid  = (int)((blockIdx.x * 256 + threadIdx.x) >> 6);
  const int lane = threadIdx.x & 63;
  const int s = wid >> 5;
  const int h = wid & 31;
  const size_t idx = (size_t)s*D_ + h*HD_ + lane;
  float val = q[idx];
  const float c  = cosT[s*32 + (lane >> 1)];
  const float sn = sinT[s*32 + (lane >> 1)];
  const float partner = __shfl_xor(val, 1);
  const float ro = (lane & 1) ? fmaf(partner, sn, val*c)
                              : fmaf(val, c, -partner*sn);
  float ssq = ro * ro;
#pragma unroll
  for (int off = 32; off >= 1; off >>= 1) ssq += __shfl_xor(ssq, off);
  const float rinv = rsqrtf(ssq * (1.0f/64.0f) + 1e-5f);
  qbf[idx] = (__bf16)(ro * rinv * w[lane] * 0.180336880111120426f);
}

// ---------------- RoPE + RMSNorm, k variant: kp in place + kbf(bf16) -----
__global__ __launch_bounds__(256) void rope_norm_k(
    float* __restrict__ k, const float* __restrict__ cosT,
    const float* __restrict__ sinT, const float* __restrict__ w,
    __bf16* __restrict__ kbf) {
  const int wid  = (int)((blockIdx.x * 256 + threadIdx.x) >> 6);
  const int lane = threadIdx.x & 63;
  const int s   = wid >> 3;
  const int kvh = wid & 7;
  const size_t idx = (size_t)s*(NKV_*HD_) + kvh*HD_ + lane;
  float val = k[idx];
  const float c  = cosT[s*32 + (lane >> 1)];
  const float sn = sinT[s*32 + (lane >> 1)];
  const float partner = __shfl_xor(val, 1);
  const float ro = (lane & 1) ? fmaf(partner, sn, val*c)
                              : fmaf(val, c, -partner*sn);
  float ssq = ro * ro;
#pragma unroll
  for (int off = 32; off >= 1; off >>= 1) ssq += __shfl_xor(ssq, off);
  const float rinv = rsqrtf(ssq * (1.0f/64.0f) + 1e-5f);
  const float res = ro * rinv * w[lane];
  k[idx] = res;
  kbf[idx] = (__bf16)res;
}

// ---------------- khT output: khT[h][d][s] = k_post[kvh=h/4][s][d] --------
__global__ __launch_bounds__(256) void transpose_khT(
    const float* __restrict__ kpost, float* __restrict__ khT) {
  __shared__ float tl[64][68];
  const int s0  = blockIdx.x * 64;
  const int kvh = blockIdx.y;
  const int t = threadIdx.x;
  {
    const int d0 = (t & 15) * 4;
    const int sl = t >> 4;
#pragma unroll
    for (int rep = 0; rep < 4; ++rep) {
      const int srow = sl + rep*16;
      float4 v = *reinterpret_cast<const float4*>(
          &kpost[(size_t)(s0 + srow)*(NKV_*HD_) + kvh*HD_ + d0]);
      tl[d0+0][srow]=v.x; tl[d0+1][srow]=v.y; tl[d0+2][srow]=v.z; tl[d0+3][srow]=v.w;
    }
  }
  __syncthreads();
  {
    const int d  = t >> 2;
    const int s4 = (t & 3) * 16;
#pragma unroll
    for (int c = 0; c < 4; ++c) {
      float4 v;
      v.x = tl[d][s4+c*4+0]; v.y = tl[d][s4+c*4+1];
      v.z = tl[d][s4+c*4+2]; v.w = tl[d][s4+c*4+3];
#pragma unroll
      for (int r = 0; r < 4; ++r) {
        *reinterpret_cast<float4*>(
            &khT[((size_t)(kvh*4 + r)*HD_ + d)*S_ + s0 + s4 + c*4]) = v;
      }
    }
  }
}

// ---------------- V: vh output (f32, replicated) + vT global (bf16) -------
__global__ __launch_bounds__(256) void transpose_v(
    const float* __restrict__ vp, float* __restrict__ vh,
    __bf16* __restrict__ vtbf) {
  __shared__ float tl[64][68];
  const int s0  = blockIdx.x * 64;
  const int kvh = blockIdx.y;
  const int t = threadIdx.x;
  const int srow = t >> 2, dc = (t & 3) * 16;
  const float* src = &vp[(size_t)(s0 + srow)*(NKV_*HD_) + kvh*HD_ + dc];
  float4 a = reinterpret_cast<const float4*>(src)[0];
  float4 b = reinterpret_cast<const float4*>(src)[1];
  float4 c = reinterpret_cast<const float4*>(src)[2];
  float4 d = reinterpret_cast<const float4*>(src)[3];
  *reinterpret_cast<float4*>(&tl[srow][dc])      = a;
  *reinterpret_cast<float4*>(&tl[srow][dc + 4])  = b;
  *reinterpret_cast<float4*>(&tl[srow][dc + 8])  = c;
  *reinterpret_cast<float4*>(&tl[srow][dc + 12]) = d;
#pragma unroll
  for (int r = 0; r < 4; ++r) {
    float* dst = &vh[((size_t)(kvh*4 + r)*S_ + s0 + srow)*HD_ + dc];
    reinterpret_cast<float4*>(dst)[0] = a;
    reinterpret_cast<float4*>(dst)[1] = b;
    reinterpret_cast<float4*>(dst)[2] = c;
    reinterpret_cast<float4*>(dst)[3] = d;
  }
  __syncthreads();
  const int dr = t >> 2, sc = (t & 3) * 16;
  __bf16 vals[16];
#pragma unroll
  for (int i = 0; i < 16; ++i) vals[i] = (__bf16)tl[sc + i][dr];
  uint4* dst = reinterpret_cast<uint4*>(&vtbf[((size_t)(kvh*64 + dr))*S_ + s0 + sc]);
  dst[0] = reinterpret_cast<uint4*>(vals)[0];
  dst[1] = reinterpret_cast<uint4*>(vals)[1];
}

// ---------------- flash helpers (swapped-operand T12 form) ----------------
__device__ __forceinline__ uint pack2bf(float a, float b) {
  __bf16 x = (__bf16)a, y = (__bf16)b;
  const uint ux = (uint)*reinterpret_cast<ushort*>(&x);
  const uint uy = (uint)*reinterpret_cast<ushort*>(&y);
  return ux | (uy << 16);
}

// S^T = K * Q^T : lane holds S[key = nb*16+lg*4+r][qrow = wg*16 + l15]
__device__ __forceinline__ void qk_tile_T(
    const char* kldh, bf16x8 qf0, bf16x8 qf1, f32x4 (&s_)[4],
    int l15, int lg) {
  __builtin_amdgcn_s_setprio(1);
#pragma unroll
  for (int nb = 0; nb < 4; ++nb) {
    const int row = nb*16 + l15;                 // key row in kld
    const int bc  = lg*16;
    const bf16x8 kb0 = *reinterpret_cast<const bf16x8*>(
        kldh + row*128 + ((bc)      ^ ((row & 7) << 4)));
    const bf16x8 kb1 = *reinterpret_cast<const bf16x8*>(
        kldh + row*128 + ((bc + 64) ^ ((row & 7) << 4)));
    f32x4 t = f32x4{0.f, 0.f, 0.f, 0.f};
    t = __builtin_amdgcn_mfma_f32_16x16x32_bf16(kb0, qf0, t, 0, 0, 0);  // swapped
    t = __builtin_amdgcn_mfma_f32_16x16x32_bf16(kb1, qf1, t, 0, 0, 0);
    s_[nb] = t;
  }
  __builtin_amdgcn_s_setprio(0);
}

// exp2-domain softmax with lane-local rows (m_, l_ scalars) + swapped PV.
// pldw: per-wave [16 qrow][64 key] bf16, kld-style XOR swizzle.
__device__ __forceinline__ void softmax_pv_T(
    f32x4 (&s_)[4], float& m_, float& l_, f32x4 (&o_)[4],
    char* pldw, const char* vbase, int l15, int lg) {
  float mx = fmaxf(fmaxf(s_[0][0], s_[0][1]), fmaxf(s_[0][2], s_[0][3]));
#pragma unroll
  for (int nb = 1; nb < 4; ++nb) {
    mx = fmaxf(mx, fmaxf(fmaxf(s_[nb][0], s_[nb][1]),
                         fmaxf(s_[nb][2], s_[nb][3])));
  }
  mx = fmaxf(mx, __shfl_xor(mx, 16));
  mx = fmaxf(mx, __shfl_xor(mx, 32));
  const float mnew = fmaxf(m_, mx);
  const float scl = exp2f(m_ - mnew);
  m_ = mnew;

  const int swz = (l15 & 7) << 4;
  float ls = 0.f;
#pragma unroll
  for (int nb = 0; nb < 4; ++nb) {
    float p0 = exp2f(s_[nb][0] - mnew);
    float p1 = exp2f(s_[nb][1] - mnew);
    float p2 = exp2f(s_[nb][2] - mnew);
    float p3 = exp2f(s_[nb][3] - mnew);
    ls += (p0 + p1) + (p2 + p3);
    *reinterpret_cast<uint*>(pldw + ((l15*128 + nb*32 + lg*8)     ^ swz)) = pack2bf(p0, p1);
    *reinterpret_cast<uint*>(pldw + ((l15*128 + nb*32 + lg*8 + 4) ^ swz)) = pack2bf(p2, p3);
  }
  ls += __shfl_xor(ls, 16);
  ls += __shfl_xor(ls, 32);
  l_ = l_*scl + ls;
#pragma unroll
  for (int nb = 0; nb < 4; ++nb) {
    o_[nb][0] *= scl; o_[nb][1] *= scl; o_[nb][2] *= scl; o_[nb][3] *= scl;
  }

  const bf16x8 pb0 = *reinterpret_cast<const bf16x8*>(
      pldw + ((l15*128 + lg*16)      ^ swz));
  const bf16x8 pb1 = *reinterpret_cast<const bf16x8*>(
      pldw + ((l15*128 + lg*16 + 64) ^ swz));

  __builtin_amdgcn_s_setprio(1);
#pragma unroll
  for (int nb = 0; nb < 4; ++nb) {
    const int row = nb*16 + l15;                 // d row in vtl
    const int bc  = lg*16;
    const bf16x8 v0 = *reinterpret_cast<const bf16x8*>(
        vbase + row*128 + ((bc)      ^ ((row & 7) << 4)));
    const bf16x8 v1 = *reinterpret_cast<const bf16x8*>(
        vbase + row*128 + ((bc + 64) ^ ((row & 7) << 4)));
    f32x4 t = o_[nb];
    t = __builtin_amdgcn_mfma_f32_16x16x32_bf16(v0, pb0, t, 0, 0, 0);  // O^T
    t = __builtin_amdgcn_mfma_f32_16x16x32_bf16(v1, pb1, t, 0, 0, 0);
    o_[nb] = t;
  }
  __builtin_amdgcn_s_setprio(0);
}

// causal mask in S^T layout: key = nb*16+lg*4+r, qrow = wg*16 + l15
__device__ __forceinline__ void mask_diag_T(f32x4 (&s_)[4], int l15, int lg, int wg) {
  const int qrow = wg*16 + l15;
#pragma unroll
  for (int nb = 0; nb < 4; ++nb)
#pragma unroll
    for (int r = 0; r < 4; ++r)
      if (nb*16 + lg*4 + r > qrow) s_[nb][r] = -1e30f;
}

// ---------------- causal flash attention, paired q-tiles, kt-parity split -
__global__ __launch_bounds__(512, 4) void flash_attn_mfma(
    const __bf16* __restrict__ qbf, const __bf16* __restrict__ kbf,
    const __bf16* __restrict__ vtbf, __bf16* __restrict__ ypre) {
  __shared__ __align__(16) char smem[49152];

  const int h   = blockIdx.y;
  const int pi  = blockIdx.x;       // 0..15
  const int qbA = pi, qbB = 31 - pi;
  const int SS  = (qbB >> 1) + 1;   // super-steps (2 kts each)
  const int kvh = h >> 2;
  const int tid = threadIdx.x;
  const int l   = tid & 63;
  const int w   = tid >> 6;         // 0..7
  const int g   = tid >> 8;         // kt parity group
  const int wg  = w & 3;            // row-group within q-tile
  const int l15 = l & 15;
  const int lg  = l >> 4;

  char* kldg = smem + g*8192;
  char* vtlg = smem + 16384 + g*8192;
  char* pldw = smem + 32768 + w*2048;

  const int ts = tid & 255;
  const int j  = ts >> 2;
  const int c0 = (ts & 3) * 16;
  const int b0 = (j*128 + c0*2)      ^ ((j & 7) << 4);
  const int b1 = (j*128 + c0*2 + 16) ^ ((j & 7) << 4);
  const __bf16* ksrc = kbf  + (size_t)(g*64 + j)*(NKV_*HD_) + kvh*HD_ + c0;
  const __bf16* vsrc = vtbf + (size_t)(kvh*64 + j)*S_ + g*64 + c0;

  bf16x8 qfA0, qfA1, qfB0, qfB1;
  {
    const __bf16* qa = qbf + (size_t)(qbA*64 + wg*16 + l15)*D_ + h*HD_ + lg*8;
    qfA0 = *reinterpret_cast<const bf16x8*>(qa);
    qfA1 = *reinterpret_cast<const bf16x8*>(qa + 32);
    const __bf16* qb = qbf + (size_t)(qbB*64 + wg*16 + l15)*D_ + h*HD_ + lg*8;
    qfB0 = *reinterpret_cast<const bf16x8*>(qb);
    qfB1 = *reinterpret_cast<const bf16x8*>(qb + 32);
  }

  f32x4 oA[4], oB[4];
#pragma unroll
  for (int nb = 0; nb < 4; ++nb) {
    oA[nb] = f32x4{0.f, 0.f, 0.f, 0.f};
    oB[nb] = f32x4{0.f, 0.f, 0.f, 0.f};
  }
  float mA = -1e30f, lA = 0.f, mB = -1e30f, lB = 0.f;

  uint4 kr0 = reinterpret_cast<const uint4*>(ksrc)[0];
  uint4 kr1 = reinterpret_cast<const uint4*>(ksrc + 8)[0];
  uint4 vr0 = reinterpret_cast<const uint4*>(vsrc)[0];
  uint4 vr1 = reinterpret_cast<const uint4*>(vsrc + 8)[0];

  for (int st = 0; st < SS; ++st) {
    __syncthreads();
    *reinterpret_cast<uint4*>(kldg + b0) = kr0;
    *reinterpret_cast<uint4*>(kldg + b1) = kr1;
    *reinterpret_cast<uint4*>(vtlg + b0) = vr0;
    *reinterpret_cast<uint4*>(vtlg + b1) = vr1;
    __syncthreads();

    if (st + 1 < SS) {
      const __bf16* kn = ksrc + (size_t)(st + 1)*128*(NKV_*HD_);
      const __bf16* vn = vsrc + (size_t)(st + 1)*128;
      kr0 = reinterpret_cast<const uint4*>(kn)[0];
      kr1 = reinterpret_cast<const uint4*>(kn + 8)[0];
      vr0 = reinterpret_cast<const uint4*>(vn)[0];
      vr1 = reinterpret_cast<const uint4*>(vn + 8)[0];
    }

    const int kt = 2*st + g;
    if (kt <= qbB) {
      f32x4 s_[4];
      qk_tile_T(kldg, qfB0, qfB1, s_, l15, lg);
      if (kt == qbB) mask_diag_T(s_, l15, lg, wg);
      softmax_pv_T(s_, mB, lB, oB, pldw, vtlg, l15, lg);
    }
    if (kt <= qbA) {
      f32x4 s_[4];
      qk_tile_T(kldg, qfA0, qfA1, s_, l15, lg);
      if (kt == qbA) mask_diag_T(s_, l15, lg, wg);
      softmax_pv_T(s_, mA, lA, oA, pldw, vtlg, l15, lg);
    }
  }

  // ---- merge parities (group1 -> LDS, group0 combines) ----
  float* ox = reinterpret_cast<float*>(smem);                 // 256 lanes x 17
  float* ml = reinterpret_cast<float*>(smem + 20480);         // 256 lanes x 9
  float* po = ox + (wg*64 + l)*17;
  float* pm = ml + (wg*64 + l)*9;

  __syncthreads();
  if (g == 1) {
#pragma unroll
    for (int nb = 0; nb < 4; ++nb)
#pragma unroll
      for (int r = 0; r < 4; ++r) po[nb*4 + r] = oB[nb][r];
    pm[0] = mB; pm[1] = lB;
  }
  __syncthreads();
  if (g == 0) {
    const float m1 = pm[0], l1 = pm[1];
    const float m = fmaxf(mB, m1);
    const float s0 = exp2f(mB - m), s1 = exp2f(m1 - m);
    lB = lB*s0 + l1*s1;
#pragma unroll
    for (int nb = 0; nb < 4; ++nb)
#pragma unroll
      for (int r = 0; r < 4; ++r)
        oB[nb][r] = oB[nb][r]*s0 + po[nb*4 + r]*s1;
  }
  __syncthreads();
  if (g == 1) {
#pragma unroll
    for (int nb = 0; nb < 4; ++nb)
#pragma unroll
      for (int r = 0; r < 4; ++r) po[nb*4 + r] = oA[nb][r];
    pm[0] = mA; pm[1] = lA;
  }
  __syncthreads();
  if (g == 0) {
    const float m1 = pm[0], l1 = pm[1];
    const float m = fmaxf(mA, m1);
    const float s0 = exp2f(mA - m), s1 = exp2f(m1 - m);
    lA = lA*s0 + l1*s1;
#pragma unroll
    for (int nb = 0; nb < 4; ++nb)
#pragma unroll
      for (int r = 0; r < 4; ++r)
        oA[nb][r] = oA[nb][r]*s0 + po[nb*4 + r]*s1;

    const float rlA = 1.0f / lA, rlB = 1.0f / lB;
    const size_t rowA = (size_t)(qbA*64 + wg*16 + l15)*D_ + h*HD_;
    const size_t rowB = (size_t)(qbB*64 + wg*16 + l15)*D_ + h*HD_;
#pragma unroll
    for (int nb = 0; nb < 4; ++nb) {
      uint2 pa, pb;
      pa.x = pack2bf(oA[nb][0]*rlA, oA[nb][1]*rlA);
      pa.y = pack2bf(oA[nb][2]*rlA, oA[nb][3]*rlA);
      pb.x = pack2bf(oB[nb][0]*rlB, oB[nb][1]*rlB);
      pb.y = pack2bf(oB[nb][2]*rlB, oB[nb][3]*rlB);
      *reinterpret_cast<uint2*>(&ypre[rowA + nb*16 + lg*4]) = pa;
      *reinterpret_cast<uint2*>(&ypre[rowB + nb*16 + lg*4]) = pb;
    }
  }
}

// --------------------------------------------------------------------------
extern "C" void kernel_launch(void* const* d_in, const int* in_sizes, int n_in,
                              void* d_out, int out_size, void* d_ws, size_t ws_size,
                              hipStream_t stream) {
  (void)in_sizes; (void)n_in; (void)out_size;
  const float* hs   = (const float*)d_in[0];
  const float* fcos = (const float*)d_in[1];
  const float* fsin = (const float*)d_in[2];
  const float* wq = (const float*)d_in[4];
  const float* wk = (const float*)d_in[5];
  const float* wv = (const float*)d_in[6];
  const float* wo = (const float*)d_in[7];
  const float* qw = (const float*)d_in[8];
  const float* kw = (const float*)d_in[9];

  float* out = (float*)d_out;
  float* y   = out;                 // 2048*2048
  float* khT = out + 4194304;       // 32*64*2048
  float* vh  = out + 8388608;       // 32*2048*64

  __bf16* qbf   = (__bf16*)y;
  __bf16* kbf   = (__bf16*)((char*)y + 8*1024*1024);
  __bf16* vtbf  = (__bf16*)((char*)y + 10*1024*1024);
  __bf16* hs_bf = (__bf16*)khT;
  __bf16* wq_bf = (__bf16*)((char*)khT + 8*1024*1024);
  __bf16* wk_bf = (__bf16*)vh;
  __bf16* wv_bf = (__bf16*)((char*)vh + 2*1024*1024);

  const size_t need = (size_t)40 * 1024 * 1024;
  if (ws_size < need) return;
  char* ws = (char*)d_ws;
  float*  qp      = (float*)(ws);                    // 16MB
  float*  kp      = (float*)(ws + 16*1024*1024);     //  4MB
  float*  vp      = (float*)(ws + 20*1024*1024);     //  4MB
  __bf16* ypre_bf = (__bf16*)(ws + 24*1024*1024);    //  8MB
  __bf16* wo_bf   = (__bf16*)(ws + 32*1024*1024);    //  8MB

  cvt_all<<<14336, 256, 0, stream>>>(hs, wq, wk, wv, wo,
                                     hs_bf, wq_bf, wk_bf, wv_bf, wo_bf);

  gemm_qkv<<<dim3(24, 16), 256, 0, stream>>>(hs_bf, wq_bf, wk_bf, wv_bf, qp, kp, vp);

  rope_norm_q<<<16384, 256, 0, stream>>>(qp, fcos, fsin, qw, qbf);
  rope_norm_k<<< 4096, 256, 0, stream>>>(kp, fcos, fsin, kw, kbf);

  transpose_khT<<<dim3(32, 8), 256, 0, stream>>>(kp, khT);
  transpose_v<<<dim3(32, 8), 256, 0, stream>>>(vp, vh, vtbf);

  flash_attn_mfma<<<dim3(16, 32), 512, 0, stream>>>(qbf, kbf, vtbf, ypre_bf);

  gemm_wo<<<dim3(16, 16), 256, 0, stream>>>(ypre_bf, wo_bf, y);
}

// Round 13
// 154.191 us; speedup vs baseline: 1.3206x; 1.0334x over previous
//
#include <hip/hip_runtime.h>
#include <cstdint>
#include <cstddef>

#define S_   2048
#define D_   2048
#define NH_  32
#define NKV_ 8
#define HD_  64

using bf16x8 = __attribute__((ext_vector_type(8))) __bf16;
using f32x4  = __attribute__((ext_vector_type(4))) float;

#define AS_GLOBAL(p) (const __attribute__((address_space(1))) void*)(p)
#define AS_LDS(p)    (__attribute__((address_space(3))) void*)(p)

// ---------------- fused f32 -> bf16 bulk convert (5 regions) --------------
__global__ __launch_bounds__(256) void cvt_all(
    const float* __restrict__ hs, const float* __restrict__ wq,
    const float* __restrict__ wk, const float* __restrict__ wv,
    const float* __restrict__ wo,
    __bf16* __restrict__ hs_bf, __bf16* __restrict__ wq_bf,
    __bf16* __restrict__ wk_bf, __bf16* __restrict__ wv_bf,
    __bf16* __restrict__ wo_bf) {
  int i = blockIdx.x * 256 + threadIdx.x;   // float4 index; total 3670016
  const float* src; __bf16* dst; int base;
  if (i < 1048576)      { src = hs; dst = hs_bf; base = 0; }
  else if (i < 2097152) { src = wq; dst = wq_bf; base = 1048576; }
  else if (i < 2359296) { src = wk; dst = wk_bf; base = 2097152; }
  else if (i < 2621440) { src = wv; dst = wv_bf; base = 2359296; }
  else                  { src = wo; dst = wo_bf; base = 2621440; }
  i -= base;
  const float4 v = reinterpret_cast<const float4*>(src)[i];
  __bf16 t[4] = {(__bf16)v.x, (__bf16)v.y, (__bf16)v.z, (__bf16)v.w};
  reinterpret_cast<uint2*>(dst)[i] = *reinterpret_cast<uint2*>(t);
}

// ---------------- GEMM fragment compute (shared by both pipelines) --------
__device__ __forceinline__ void gemm_compute_step(
    const char* ldsA, const char* ldsB, f32x4 (&acc)[4][4],
    int l15, int lg, int wm, int wn) {
  bf16x8 af[4][2], bfr[4][2];
#pragma unroll
  for (int f = 0; f < 4; ++f) {
    const int arow = wm*64 + f*16 + l15;
    const int brow = wn*64 + f*16 + l15;
#pragma unroll
    for (int ks = 0; ks < 2; ++ks) {
      af[f][ks] = *reinterpret_cast<const bf16x8*>(
          ldsA + arow*128 + (((ks*4 + lg) ^ (arow & 7)) << 4));
      bfr[f][ks] = *reinterpret_cast<const bf16x8*>(
          ldsB + brow*128 + (((ks*4 + lg) ^ (brow & 7)) << 4));
    }
  }
#pragma unroll
  for (int mf = 0; mf < 4; ++mf)
#pragma unroll
    for (int nf = 0; nf < 4; ++nf) {
      acc[mf][nf] = __builtin_amdgcn_mfma_f32_16x16x32_bf16(
          af[mf][0], bfr[nf][0], acc[mf][nf], 0, 0, 0);
      acc[mf][nf] = __builtin_amdgcn_mfma_f32_16x16x32_bf16(
          af[mf][1], bfr[nf][1], acc[mf][nf], 0, 0, 0);
    }
}

// ---------------- bf16 MFMA GEMM, 2-buffer (depth-1) pipeline -------------
// Used by qkv (blocks can be 2-resident at 64KB LDS -> TLP hides latency).
__device__ __forceinline__ void gemm_tile_128(
    const __bf16* __restrict__ A, const __bf16* __restrict__ B,
    float* __restrict__ C, int K, int N, int m0, int n0) {
  __shared__ __align__(16) char lds[2][32768];   // [buf][A 16K | B 16K]
  const int tid = threadIdx.x;
  const int l = tid & 63;
  const int w = tid >> 6;
  const int l15 = l & 15, lg = l >> 4;
  const int wm = w >> 1, wn = w & 1;

  f32x4 acc[4][4] = {};

  const int srow   = tid >> 3;
  const int schunk = (tid & 7) ^ (srow & 7);
  const __bf16* gA = A + (size_t)(m0 + srow) * K + schunk * 8;
  const __bf16* gB = B + (size_t)(n0 + srow) * K + schunk * 8;
  const int ldst = tid * 16;
  const int nt = K >> 6;

#pragma unroll
  for (int i = 0; i < 4; ++i) {
    __builtin_amdgcn_global_load_lds(AS_GLOBAL(gA + (size_t)i*32*K),
                                     AS_LDS(&lds[0][i*4096 + ldst]), 16, 0, 0);
    __builtin_amdgcn_global_load_lds(AS_GLOBAL(gB + (size_t)i*32*K),
                                     AS_LDS(&lds[0][16384 + i*4096 + ldst]), 16, 0, 0);
  }
  __syncthreads();

  int cur = 0;
  for (int t = 0; t < nt; ++t) {
    if (t + 1 < nt) {
      const int k0 = (t + 1) * 64;
      char* dA = &lds[cur ^ 1][0];
      char* dB = &lds[cur ^ 1][16384];
#pragma unroll
      for (int i = 0; i < 4; ++i) {
        __builtin_amdgcn_global_load_lds(AS_GLOBAL(gA + (size_t)i*32*K + k0),
                                         AS_LDS(dA + i*4096 + ldst), 16, 0, 0);
        __builtin_amdgcn_global_load_lds(AS_GLOBAL(gB + (size_t)i*32*K + k0),
                                         AS_LDS(dB + i*4096 + ldst), 16, 0, 0);
      }
    }
    gemm_compute_step(&lds[cur][0], &lds[cur][16384], acc, l15, lg, wm, wn);
    __syncthreads();
    cur ^= 1;
  }

#pragma unroll
  for (int mf = 0; mf < 4; ++mf)
#pragma unroll
    for (int nf = 0; nf < 4; ++nf)
#pragma unroll
      for (int r = 0; r < 4; ++r)
        C[(size_t)(m0 + wm*64 + mf*16 + lg*4 + r) * N + n0 + wn*64 + nf*16 + l15]
            = acc[mf][nf][r];
}

// ---------------- bf16 MFMA GEMM, 3-buffer depth-2 counted-vmcnt ----------
// T4 pipeline for the 1-block/CU regime (gemm_wo): loads for tile t+1 stay in
// flight across the barrier (s_waitcnt vmcnt(8), raw s_barrier — m201 pattern).
// Buffer-reuse safety: stage(t+2) at iter t overwrites the buffer computed at
// t-1; the iter-top barrier guarantees all waves finished that compute.
__device__ __forceinline__ void gemm_tile_128_d2(
    const __bf16* __restrict__ A, const __bf16* __restrict__ B,
    float* __restrict__ C, int K, int N, int m0, int n0) {
  __shared__ __align__(16) char lds[3][32768];   // [buf][A 16K | B 16K]
  const int tid = threadIdx.x;
  const int l = tid & 63;
  const int w = tid >> 6;
  const int l15 = l & 15, lg = l >> 4;
  const int wm = w >> 1, wn = w & 1;

  f32x4 acc[4][4] = {};

  const int srow   = tid >> 3;
  const int schunk = (tid & 7) ^ (srow & 7);
  const __bf16* gA = A + (size_t)(m0 + srow) * K + schunk * 8;
  const __bf16* gB = B + (size_t)(n0 + srow) * K + schunk * 8;
  const int ldst = tid * 16;
  const int nt = K >> 6;

  // prologue: stage tiles 0 and 1 (16 loads/thread outstanding)
#pragma unroll
  for (int i = 0; i < 4; ++i) {
    __builtin_amdgcn_global_load_lds(AS_GLOBAL(gA + (size_t)i*32*K),
                                     AS_LDS(&lds[0][i*4096 + ldst]), 16, 0, 0);
    __builtin_amdgcn_global_load_lds(AS_GLOBAL(gB + (size_t)i*32*K),
                                     AS_LDS(&lds[0][16384 + i*4096 + ldst]), 16, 0, 0);
  }
#pragma unroll
  for (int i = 0; i < 4; ++i) {
    __builtin_amdgcn_global_load_lds(AS_GLOBAL(gA + (size_t)i*32*K + 64),
                                     AS_LDS(&lds[1][i*4096 + ldst]), 16, 0, 0);
    __builtin_amdgcn_global_load_lds(AS_GLOBAL(gB + (size_t)i*32*K + 64),
                                     AS_LDS(&lds[1][16384 + i*4096 + ldst]), 16, 0, 0);
  }

  char* p0 = &lds[0][0];   // read target
  char* p1 = &lds[1][0];   // in flight
  char* p2 = &lds[2][0];   // stage target

  for (int t = 0; t < nt; ++t) {
    // wave-local: my tile-t loads have landed; tile-t+1 loads stay in flight
    if (t + 1 < nt) asm volatile("s_waitcnt vmcnt(8)" ::: "memory");
    else            asm volatile("s_waitcnt vmcnt(0)" ::: "memory");
    __builtin_amdgcn_s_barrier();   // raw: no vmcnt(0) drain

    if (t + 2 < nt) {
      const int k0 = (t + 2) * 64;
#pragma unroll
      for (int i = 0; i < 4; ++i) {
        __builtin_amdgcn_global_load_lds(AS_GLOBAL(gA + (size_t)i*32*K + k0),
                                         AS_LDS(p2 + i*4096 + ldst), 16, 0, 0);
        __builtin_amdgcn_global_load_lds(AS_GLOBAL(gB + (size_t)i*32*K + k0),
                                         AS_LDS(p2 + 16384 + i*4096 + ldst), 16, 0, 0);
      }
    }

    gemm_compute_step(p0, p0 + 16384, acc, l15, lg, wm, wn);

    char* tmp = p0; p0 = p1; p1 = p2; p2 = tmp;   // rotate buffers
  }

#pragma unroll
  for (int mf = 0; mf < 4; ++mf)
#pragma unroll
    for (int nf = 0; nf < 4; ++nf)
#pragma unroll
      for (int r = 0; r < 4; ++r)
        C[(size_t)(m0 + wm*64 + mf*16 + lg*4 + r) * N + n0 + wn*64 + nf*16 + l15]
            = acc[mf][nf][r];
}

// fused Q/K/V projection: grid.x 0..15 -> wq tiles, 16..19 -> wk, 20..23 -> wv
__global__ __launch_bounds__(256) void gemm_qkv(
    const __bf16* __restrict__ hs,
    const __bf16* __restrict__ wq, const __bf16* __restrict__ wk,
    const __bf16* __restrict__ wv,
    float* __restrict__ qp, float* __restrict__ kp, float* __restrict__ vp) {
  const int bx = blockIdx.x;
  const __bf16* Bm; float* Cm; int N, n0;
  if (bx < 16)      { Bm = wq; Cm = qp; N = 2048; n0 = bx * 128; }
  else if (bx < 20) { Bm = wk; Cm = kp; N = 512;  n0 = (bx - 16) * 128; }
  else              { Bm = wv; Cm = vp; N = 512;  n0 = (bx - 20) * 128; }
  gemm_tile_128(hs, Bm, Cm, 2048, N, blockIdx.y * 128, n0);
}

__global__ __launch_bounds__(256) void gemm_wo(
    const __bf16* __restrict__ ypre, const __bf16* __restrict__ wo,
    float* __restrict__ y) {
  gemm_tile_128_d2(ypre, wo, y, 2048, 2048, blockIdx.y * 128, blockIdx.x * 128);
}

// ---------------- RoPE + RMSNorm, q variant -------------------------------
__global__ __launch_bounds__(256) void rope_norm_q(
    const float* __restrict__ q, const float* __restrict__ cosT,
    const float* __restrict__ sinT, const float* __restrict__ w,
    __bf16* __restrict__ qbf) {
  const int wid  = (int)((blockIdx.x * 256 + threadIdx.x) >> 6);
  const int lane = threadIdx.x & 63;
  const int s = wid >> 5;
  const int h = wid & 31;
  const size_t idx = (size_t)s*D_ + h*HD_ + lane;
  float val = q[idx];
  const float c  = cosT[s*32 + (lane >> 1)];
  const float sn = sinT[s*32 + (lane >> 1)];
  const float partner = __shfl_xor(val, 1);
  const float ro = (lane & 1) ? fmaf(partner, sn, val*c)
                              : fmaf(val, c, -partner*sn);
  float ssq = ro * ro;
#pragma unroll
  for (int off = 32; off >= 1; off >>= 1) ssq += __shfl_xor(ssq, off);
  const float rinv = rsqrtf(ssq * (1.0f/64.0f) + 1e-5f);
  qbf[idx] = (__bf16)(ro * rinv * w[lane] * 0.180336880111120426f);
}

// ---------------- RoPE + RMSNorm, k variant: kp in place + kbf(bf16) -----
__global__ __launch_bounds__(256) void rope_norm_k(
    float* __restrict__ k, const float* __restrict__ cosT,
    const float* __restrict__ sinT, const float* __restrict__ w,
    __bf16* __restrict__ kbf) {
  const int wid  = (int)((blockIdx.x * 256 + threadIdx.x) >> 6);
  const int lane = threadIdx.x & 63;
  const int s   = wid >> 3;
  const int kvh = wid & 7;
  const size_t idx = (size_t)s*(NKV_*HD_) + kvh*HD_ + lane;
  float val = k[idx];
  const float c  = cosT[s*32 + (lane >> 1)];
  const float sn = sinT[s*32 + (lane >> 1)];
  const float partner = __shfl_xor(val, 1);
  const float ro = (lane & 1) ? fmaf(partner, sn, val*c)
                              : fmaf(val, c, -partner*sn);
  float ssq = ro * ro;
#pragma unroll
  for (int off = 32; off >= 1; off >>= 1) ssq += __shfl_xor(ssq, off);
  const float rinv = rsqrtf(ssq * (1.0f/64.0f) + 1e-5f);
  const float res = ro * rinv * w[lane];
  k[idx] = res;
  kbf[idx] = (__bf16)res;
}

// ---------------- khT output: khT[h][d][s] = k_post[kvh=h/4][s][d] --------
__global__ __launch_bounds__(256) void transpose_khT(
    const float* __restrict__ kpost, float* __restrict__ khT) {
  __shared__ float tl[64][68];
  const int s0  = blockIdx.x * 64;
  const int kvh = blockIdx.y;
  const int t = threadIdx.x;
  {
    const int d0 = (t & 15) * 4;
    const int sl = t >> 4;
#pragma unroll
    for (int rep = 0; rep < 4; ++rep) {
      const int srow = sl + rep*16;
      float4 v = *reinterpret_cast<const float4*>(
          &kpost[(size_t)(s0 + srow)*(NKV_*HD_) + kvh*HD_ + d0]);
      tl[d0+0][srow]=v.x; tl[d0+1][srow]=v.y; tl[d0+2][srow]=v.z; tl[d0+3][srow]=v.w;
    }
  }
  __syncthreads();
  {
    const int d  = t >> 2;
    const int s4 = (t & 3) * 16;
#pragma unroll
    for (int c = 0; c < 4; ++c) {
      float4 v;
      v.x = tl[d][s4+c*4+0]; v.y = tl[d][s4+c*4+1];
      v.z = tl[d][s4+c*4+2]; v.w = tl[d][s4+c*4+3];
#pragma unroll
      for (int r = 0; r < 4; ++r) {
        *reinterpret_cast<float4*>(
            &khT[((size_t)(kvh*4 + r)*HD_ + d)*S_ + s0 + s4 + c*4]) = v;
      }
    }
  }
}

// ---------------- V: vh output (f32, replicated) + vT global (bf16) -------
__global__ __launch_bounds__(256) void transpose_v(
    const float* __restrict__ vp, float* __restrict__ vh,
    __bf16* __restrict__ vtbf) {
  __shared__ float tl[64][68];
  const int s0  = blockIdx.x * 64;
  const int kvh = blockIdx.y;
  const int t = threadIdx.x;
  const int srow = t >> 2, dc = (t & 3) * 16;
  const float* src = &vp[(size_t)(s0 + srow)*(NKV_*HD_) + kvh*HD_ + dc];
  float4 a = reinterpret_cast<const float4*>(src)[0];
  float4 b = reinterpret_cast<const float4*>(src)[1];
  float4 c = reinterpret_cast<const float4*>(src)[2];
  float4 d = reinterpret_cast<const float4*>(src)[3];
  *reinterpret_cast<float4*>(&tl[srow][dc])      = a;
  *reinterpret_cast<float4*>(&tl[srow][dc + 4])  = b;
  *reinterpret_cast<float4*>(&tl[srow][dc + 8])  = c;
  *reinterpret_cast<float4*>(&tl[srow][dc + 12]) = d;
#pragma unroll
  for (int r = 0; r < 4; ++r) {
    float* dst = &vh[((size_t)(kvh*4 + r)*S_ + s0 + srow)*HD_ + dc];
    reinterpret_cast<float4*>(dst)[0] = a;
    reinterpret_cast<float4*>(dst)[1] = b;
    reinterpret_cast<float4*>(dst)[2] = c;
    reinterpret_cast<float4*>(dst)[3] = d;
  }
  __syncthreads();
  const int dr = t >> 2, sc = (t & 3) * 16;
  __bf16 vals[16];
#pragma unroll
  for (int i = 0; i < 16; ++i) vals[i] = (__bf16)tl[sc + i][dr];
  uint4* dst = reinterpret_cast<uint4*>(&vtbf[((size_t)(kvh*64 + dr))*S_ + s0 + sc]);
  dst[0] = reinterpret_cast<uint4*>(vals)[0];
  dst[1] = reinterpret_cast<uint4*>(vals)[1];
}

// ---------------- flash helpers (swapped-operand T12 form) ----------------
__device__ __forceinline__ uint pack2bf(float a, float b) {
  __bf16 x = (__bf16)a, y = (__bf16)b;
  const uint ux = (uint)*reinterpret_cast<ushort*>(&x);
  const uint uy = (uint)*reinterpret_cast<ushort*>(&y);
  return ux | (uy << 16);
}

// S^T = K * Q^T : lane holds S[key = nb*16+lg*4+r][qrow = wg*16 + l15]
__device__ __forceinline__ void qk_tile_T(
    const char* kldh, bf16x8 qf0, bf16x8 qf1, f32x4 (&s_)[4],
    int l15, int lg) {
  __builtin_amdgcn_s_setprio(1);
#pragma unroll
  for (int nb = 0; nb < 4; ++nb) {
    const int row = nb*16 + l15;                 // key row in kld
    const int bc  = lg*16;
    const bf16x8 kb0 = *reinterpret_cast<const bf16x8*>(
        kldh + row*128 + ((bc)      ^ ((row & 7) << 4)));
    const bf16x8 kb1 = *reinterpret_cast<const bf16x8*>(
        kldh + row*128 + ((bc + 64) ^ ((row & 7) << 4)));
    f32x4 t = f32x4{0.f, 0.f, 0.f, 0.f};
    t = __builtin_amdgcn_mfma_f32_16x16x32_bf16(kb0, qf0, t, 0, 0, 0);  // swapped
    t = __builtin_amdgcn_mfma_f32_16x16x32_bf16(kb1, qf1, t, 0, 0, 0);
    s_[nb] = t;
  }
  __builtin_amdgcn_s_setprio(0);
}

// exp2-domain softmax with lane-local rows (m_, l_ scalars) + swapped PV.
__device__ __forceinline__ void softmax_pv_T(
    f32x4 (&s_)[4], float& m_, float& l_, f32x4 (&o_)[4],
    char* pldw, const char* vbase, int l15, int lg) {
  float mx = fmaxf(fmaxf(s_[0][0], s_[0][1]), fmaxf(s_[0][2], s_[0][3]));
#pragma unroll
  for (int nb = 1; nb < 4; ++nb) {
    mx = fmaxf(mx, fmaxf(fmaxf(s_[nb][0], s_[nb][1]),
                         fmaxf(s_[nb][2], s_[nb][3])));
  }
  mx = fmaxf(mx, __shfl_xor(mx, 16));
  mx = fmaxf(mx, __shfl_xor(mx, 32));
  const float mnew = fmaxf(m_, mx);
  const float scl = exp2f(m_ - mnew);
  m_ = mnew;

  const int swz = (l15 & 7) << 4;
  float ls = 0.f;
#pragma unroll
  for (int nb = 0; nb < 4; ++nb) {
    float p0 = exp2f(s_[nb][0] - mnew);
    float p1 = exp2f(s_[nb][1] - mnew);
    float p2 = exp2f(s_[nb][2] - mnew);
    float p3 = exp2f(s_[nb][3] - mnew);
    ls += (p0 + p1) + (p2 + p3);
    *reinterpret_cast<uint*>(pldw + ((l15*128 + nb*32 + lg*8)     ^ swz)) = pack2bf(p0, p1);
    *reinterpret_cast<uint*>(pldw + ((l15*128 + nb*32 + lg*8 + 4) ^ swz)) = pack2bf(p2, p3);
  }
  ls += __shfl_xor(ls, 16);
  ls += __shfl_xor(ls, 32);
  l_ = l_*scl + ls;
#pragma unroll
  for (int nb = 0; nb < 4; ++nb) {
    o_[nb][0] *= scl; o_[nb][1] *= scl; o_[nb][2] *= scl; o_[nb][3] *= scl;
  }

  const bf16x8 pb0 = *reinterpret_cast<const bf16x8*>(
      pldw + ((l15*128 + lg*16)      ^ swz));
  const bf16x8 pb1 = *reinterpret_cast<const bf16x8*>(
      pldw + ((l15*128 + lg*16 + 64) ^ swz));

  __builtin_amdgcn_s_setprio(1);
#pragma unroll
  for (int nb = 0; nb < 4; ++nb) {
    const int row = nb*16 + l15;                 // d row in vtl
    const int bc  = lg*16;
    const bf16x8 v0 = *reinterpret_cast<const bf16x8*>(
        vbase + row*128 + ((bc)      ^ ((row & 7) << 4)));
    const bf16x8 v1 = *reinterpret_cast<const bf16x8*>(
        vbase + row*128 + ((bc + 64) ^ ((row & 7) << 4)));
    f32x4 t = o_[nb];
    t = __builtin_amdgcn_mfma_f32_16x16x32_bf16(v0, pb0, t, 0, 0, 0);  // O^T
    t = __builtin_amdgcn_mfma_f32_16x16x32_bf16(v1, pb1, t, 0, 0, 0);
    o_[nb] = t;
  }
  __builtin_amdgcn_s_setprio(0);
}

// causal mask in S^T layout: key = nb*16+lg*4+r, qrow = wg*16 + l15
__device__ __forceinline__ void mask_diag_T(f32x4 (&s_)[4], int l15, int lg, int wg) {
  const int qrow = wg*16 + l15;
#pragma unroll
  for (int nb = 0; nb < 4; ++nb)
#pragma unroll
    for (int r = 0; r < 4; ++r)
      if (nb*16 + lg*4 + r > qrow) s_[nb][r] = -1e30f;
}

// ---------------- causal flash attention, paired q-tiles, kt-parity split -
__global__ __launch_bounds__(512, 4) void flash_attn_mfma(
    const __bf16* __restrict__ qbf, const __bf16* __restrict__ kbf,
    const __bf16* __restrict__ vtbf, __bf16* __restrict__ ypre) {
  __shared__ __align__(16) char smem[49152];

  const int h   = blockIdx.y;
  const int pi  = blockIdx.x;       // 0..15
  const int qbA = pi, qbB = 31 - pi;
  const int SS  = (qbB >> 1) + 1;   // super-steps (2 kts each)
  const int kvh = h >> 2;
  const int tid = threadIdx.x;
  const int l   = tid & 63;
  const int w   = tid >> 6;         // 0..7
  const int g   = tid >> 8;         // kt parity group
  const int wg  = w & 3;            // row-group within q-tile
  const int l15 = l & 15;
  const int lg  = l >> 4;

  char* kldg = smem + g*8192;
  char* vtlg = smem + 16384 + g*8192;
  char* pldw = smem + 32768 + w*2048;

  const int ts = tid & 255;
  const int j  = ts >> 2;
  const int c0 = (ts & 3) * 16;
  const int b0 = (j*128 + c0*2)      ^ ((j & 7) << 4);
  const int b1 = (j*128 + c0*2 + 16) ^ ((j & 7) << 4);
  const __bf16* ksrc = kbf  + (size_t)(g*64 + j)*(NKV_*HD_) + kvh*HD_ + c0;
  const __bf16* vsrc = vtbf + (size_t)(kvh*64 + j)*S_ + g*64 + c0;

  bf16x8 qfA0, qfA1, qfB0, qfB1;
  {
    const __bf16* qa = qbf + (size_t)(qbA*64 + wg*16 + l15)*D_ + h*HD_ + lg*8;
    qfA0 = *reinterpret_cast<const bf16x8*>(qa);
    qfA1 = *reinterpret_cast<const bf16x8*>(qa + 32);
    const __bf16* qb = qbf + (size_t)(qbB*64 + wg*16 + l15)*D_ + h*HD_ + lg*8;
    qfB0 = *reinterpret_cast<const bf16x8*>(qb);
    qfB1 = *reinterpret_cast<const bf16x8*>(qb + 32);
  }

  f32x4 oA[4], oB[4];
#pragma unroll
  for (int nb = 0; nb < 4; ++nb) {
    oA[nb] = f32x4{0.f, 0.f, 0.f, 0.f};
    oB[nb] = f32x4{0.f, 0.f, 0.f, 0.f};
  }
  float mA = -1e30f, lA = 0.f, mB = -1e30f, lB = 0.f;

  uint4 kr0 = reinterpret_cast<const uint4*>(ksrc)[0];
  uint4 kr1 = reinterpret_cast<const uint4*>(ksrc + 8)[0];
  uint4 vr0 = reinterpret_cast<const uint4*>(vsrc)[0];
  uint4 vr1 = reinterpret_cast<const uint4*>(vsrc + 8)[0];

  for (int st = 0; st < SS; ++st) {
    __syncthreads();
    *reinterpret_cast<uint4*>(kldg + b0) = kr0;
    *reinterpret_cast<uint4*>(kldg + b1) = kr1;
    *reinterpret_cast<uint4*>(vtlg + b0) = vr0;
    *reinterpret_cast<uint4*>(vtlg + b1) = vr1;
    __syncthreads();

    if (st + 1 < SS) {
      const __bf16* kn = ksrc + (size_t)(st + 1)*128*(NKV_*HD_);
      const __bf16* vn = vsrc + (size_t)(st + 1)*128;
      kr0 = reinterpret_cast<const uint4*>(kn)[0];
      kr1 = reinterpret_cast<const uint4*>(kn + 8)[0];
      vr0 = reinterpret_cast<const uint4*>(vn)[0];
      vr1 = reinterpret_cast<const uint4*>(vn + 8)[0];
    }

    const int kt = 2*st + g;
    if (kt <= qbB) {
      f32x4 s_[4];
      qk_tile_T(kldg, qfB0, qfB1, s_, l15, lg);
      if (kt == qbB) mask_diag_T(s_, l15, lg, wg);
      softmax_pv_T(s_, mB, lB, oB, pldw, vtlg, l15, lg);
    }
    if (kt <= qbA) {
      f32x4 s_[4];
      qk_tile_T(kldg, qfA0, qfA1, s_, l15, lg);
      if (kt == qbA) mask_diag_T(s_, l15, lg, wg);
      softmax_pv_T(s_, mA, lA, oA, pldw, vtlg, l15, lg);
    }
  }

  // ---- merge parities (group1 -> LDS, group0 combines) ----
  float* ox = reinterpret_cast<float*>(smem);                 // 256 lanes x 17
  float* ml = reinterpret_cast<float*>(smem + 20480);         // 256 lanes x 9
  float* po = ox + (wg*64 + l)*17;
  float* pm = ml + (wg*64 + l)*9;

  __syncthreads();
  if (g == 1) {
#pragma unroll
    for (int nb = 0; nb < 4; ++nb)
#pragma unroll
      for (int r = 0; r < 4; ++r) po[nb*4 + r] = oB[nb][r];
    pm[0] = mB; pm[1] = lB;
  }
  __syncthreads();
  if (g == 0) {
    const float m1 = pm[0], l1 = pm[1];
    const float m = fmaxf(mB, m1);
    const float s0 = exp2f(mB - m), s1 = exp2f(m1 - m);
    lB = lB*s0 + l1*s1;
#pragma unroll
    for (int nb = 0; nb < 4; ++nb)
#pragma unroll
      for (int r = 0; r < 4; ++r)
        oB[nb][r] = oB[nb][r]*s0 + po[nb*4 + r]*s1;
  }
  __syncthreads();
  if (g == 1) {
#pragma unroll
    for (int nb = 0; nb < 4; ++nb)
#pragma unroll
      for (int r = 0; r < 4; ++r) po[nb*4 + r] = oA[nb][r];
    pm[0] = mA; pm[1] = lA;
  }
  __syncthreads();
  if (g == 0) {
    const float m1 = pm[0], l1 = pm[1];
    const float m = fmaxf(mA, m1);
    const float s0 = exp2f(mA - m), s1 = exp2f(m1 - m);
    lA = lA*s0 + l1*s1;
#pragma unroll
    for (int nb = 0; nb < 4; ++nb)
#pragma unroll
      for (int r = 0; r < 4; ++r)
        oA[nb][r] = oA[nb][r]*s0 + po[nb*4 + r]*s1;

    const float rlA = 1.0f / lA, rlB = 1.0f / lB;
    const size_t rowA = (size_t)(qbA*64 + wg*16 + l15)*D_ + h*HD_;
    const size_t rowB = (size_t)(qbB*64 + wg*16 + l15)*D_ + h*HD_;
#pragma unroll
    for (int nb = 0; nb < 4; ++nb) {
      uint2 pa, pb;
      pa.x = pack2bf(oA[nb][0]*rlA, oA[nb][1]*rlA);
      pa.y = pack2bf(oA[nb][2]*rlA, oA[nb][3]*rlA);
      pb.x = pack2bf(oB[nb][0]*rlB, oB[nb][1]*rlB);
      pb.y = pack2bf(oB[nb][2]*rlB, oB[nb][3]*rlB);
      *reinterpret_cast<uint2*>(&ypre[rowA + nb*16 + lg*4]) = pa;
      *reinterpret_cast<uint2*>(&ypre[rowB + nb*16 + lg*4]) = pb;
    }
  }
}

// --------------------------------------------------------------------------
extern "C" void kernel_launch(void* const* d_in, const int* in_sizes, int n_in,
                              void* d_out, int out_size, void* d_ws, size_t ws_size,
                              hipStream_t stream) {
  (void)in_sizes; (void)n_in; (void)out_size;
  const float* hs   = (const float*)d_in[0];
  const float* fcos = (const float*)d_in[1];
  const float* fsin = (const float*)d_in[2];
  const float* wq = (const float*)d_in[4];
  const float* wk = (const float*)d_in[5];
  const float* wv = (const float*)d_in[6];
  const float* wo = (const float*)d_in[7];
  const float* qw = (const float*)d_in[8];
  const float* kw = (const float*)d_in[9];

  float* out = (float*)d_out;
  float* y   = out;                 // 2048*2048
  float* khT = out + 4194304;       // 32*64*2048
  float* vh  = out + 8388608;       // 32*2048*64

  __bf16* qbf   = (__bf16*)y;
  __bf16* kbf   = (__bf16*)((char*)y + 8*1024*1024);
  __bf16* vtbf  = (__bf16*)((char*)y + 10*1024*1024);
  __bf16* hs_bf = (__bf16*)khT;
  __bf16* wq_bf = (__bf16*)((char*)khT + 8*1024*1024);
  __bf16* wk_bf = (__bf16*)vh;
  __bf16* wv_bf = (__bf16*)((char*)vh + 2*1024*1024);

  const size_t need = (size_t)40 * 1024 * 1024;
  if (ws_size < need) return;
  char* ws = (char*)d_ws;
  float*  qp      = (float*)(ws);                    // 16MB
  float*  kp      = (float*)(ws + 16*1024*1024);     //  4MB
  float*  vp      = (float*)(ws + 20*1024*1024);     //  4MB
  __bf16* ypre_bf = (__bf16*)(ws + 24*1024*1024);    //  8MB
  __bf16* wo_bf   = (__bf16*)(ws + 32*1024*1024);    //  8MB

  cvt_all<<<14336, 256, 0, stream>>>(hs, wq, wk, wv, wo,
                                     hs_bf, wq_bf, wk_bf, wv_bf, wo_bf);

  gemm_qkv<<<dim3(24, 16), 256, 0, stream>>>(hs_bf, wq_bf, wk_bf, wv_bf, qp, kp, vp);

  rope_norm_q<<<16384, 256, 0, stream>>>(qp, fcos, fsin, qw, qbf);
  rope_norm_k<<< 4096, 256, 0, stream>>>(kp, fcos, fsin, kw, kbf);

  transpose_khT<<<dim3(32, 8), 256, 0, stream>>>(kp, khT);
  transpose_v<<<dim3(32, 8), 256, 0, stream>>>(vp, vh, vtbf);

  flash_attn_mfma<<<dim3(16, 32), 512, 0, stream>>>(qbf, kbf, vtbf, ypre_bf);

  gemm_wo<<<dim3(16, 16), 256, 0, stream>>>(ypre_bf, wo_bf, y);
}